// Round 1
// baseline (443.007 us; speedup 1.0000x reference)
//
#include <hip/hip_runtime.h>

// PointMLP stage: KNN(24) -> groupnorm+concat -> 2x res_block (D=128) -> max over K
//                 -> 2x res_block -> gather by fps_idx.
// fp16 MFMA (16x16x32) for all GEMMs, fp32 for LN/stats/accum.
// ws layout (bytes): wp[0,256K) packed fp16 weights; idx[256K,1.79M); h0[2M,6M) fp16; h1[6M,14.7M) f32.

typedef _Float16 half8  __attribute__((ext_vector_type(8)));
typedef _Float16 half2t __attribute__((ext_vector_type(2)));
typedef float    f32x4  __attribute__((ext_vector_type(4)));

#define DEVINL __device__ __forceinline__

// ---- swizzled LDS helpers: row stride 256B, XOR 16B-chunk swizzle with (row&7) ----
DEVINL void stH(_Float16* L, int row, int col, _Float16 v) {
  const int b2 = col * 2;
  *(_Float16*)((char*)L + row * 256 + (((b2 >> 4) ^ (row & 7)) << 4) + (b2 & 15)) = v;
}
DEVINL _Float16 ldH(const _Float16* L, int row, int col) {
  const int b2 = col * 2;
  return *(const _Float16*)((const char*)L + row * 256 + (((b2 >> 4) ^ (row & 7)) << 4) + (b2 & 15));
}
DEVINL half8 ldA(const _Float16* L, int row, int ch) {
  return *(const half8*)((const char*)L + row * 256 + ((ch ^ (row & 7)) << 4));
}

// ---- 48(or 32)x128 @ 128x128 matmul: A from swizzled LDS rows, B(fp16, frag-packed) from global ----
template<int MT>
DEVINL void mm_dev(const _Float16* L, const _Float16* __restrict__ W, f32x4 acc[MT][8], int lane) {
  const int g = lane >> 4, r = lane & 15;
  #pragma unroll
  for (int s = 0; s < 4; ++s) {
    half8 bfr[8];
    #pragma unroll
    for (int t = 0; t < 8; ++t)
      bfr[t] = *(const half8*)(W + (((s * 8 + t) * 64 + lane) * 8));
    #pragma unroll
    for (int mt = 0; mt < MT; ++mt) {
      const half8 a = ldA(L, mt * 16 + r, s * 4 + g);
      #pragma unroll
      for (int t = 0; t < 8; ++t)
        acc[mt][t] = __builtin_amdgcn_mfma_f32_16x16x32_f16(a, bfr[t], acc[mt][t], 0, 0, 0);
    }
  }
}

// ---- bias + LayerNorm(g, bb) applied in-place on D-layout accumulators ----
template<int MT>
DEVINL void epi_ln(f32x4 acc[MT][8], const float* __restrict__ bv, const float* __restrict__ gv,
                   const float* __restrict__ bbv, int lane) {
  const int cr = lane & 15;
  float bp[8], gp[8], bbp[8];
  #pragma unroll
  for (int t = 0; t < 8; ++t) { bp[t] = bv[cr + 16 * t]; gp[t] = gv[cr + 16 * t]; bbp[t] = bbv[cr + 16 * t]; }
  float su[MT][4], sq[MT][4];
  #pragma unroll
  for (int mt = 0; mt < MT; ++mt)
    #pragma unroll
    for (int q = 0; q < 4; ++q) { su[mt][q] = 0.f; sq[mt][q] = 0.f; }
  #pragma unroll
  for (int mt = 0; mt < MT; ++mt)
    #pragma unroll
    for (int t = 0; t < 8; ++t)
      #pragma unroll
      for (int q = 0; q < 4; ++q) {
        const float x = acc[mt][t][q] + bp[t];
        acc[mt][t][q] = x;
        su[mt][q] += x;
        sq[mt][q] = fmaf(x, x, sq[mt][q]);
      }
  #pragma unroll
  for (int mask = 1; mask < 16; mask <<= 1) {
    #pragma unroll
    for (int mt = 0; mt < MT; ++mt)
      #pragma unroll
      for (int q = 0; q < 4; ++q) {
        su[mt][q] += __shfl_xor(su[mt][q], mask);
        sq[mt][q] += __shfl_xor(sq[mt][q], mask);
      }
  }
  #pragma unroll
  for (int mt = 0; mt < MT; ++mt)
    #pragma unroll
    for (int q = 0; q < 4; ++q) {
      const float mean = su[mt][q] * (1.f / 128.f);
      const float var  = fmaxf(sq[mt][q] * (1.f / 128.f) - mean * mean, 0.f);
      const float rstd = rsqrtf(var + 1e-5f);
      #pragma unroll
      for (int t = 0; t < 8; ++t)
        acc[mt][t][q] = (acc[mt][t][q] - mean) * rstd * gp[t] + bbp[t];
    }
}

// ---- full res_block. xres holds input X (D-layout, packed f16) on entry; updated to output.
// MODE: 0 = also store output rows to LDS (next block reads them); 1 = keep in xres only; 2 = store f32 rows to gdst.
template<int MT, int MODE>
DEVINL void res_block_dev(_Float16* L, const _Float16* __restrict__ W1, const _Float16* __restrict__ W2,
                          const float* b1, const float* g1, const float* bb1,
                          const float* b2, const float* g2, const float* bb2,
                          half2t xres[MT][8][2], int lane, float* __restrict__ gdst) {
  const int g = lane >> 4, cr = lane & 15;
  f32x4 acc[MT][8];
  #pragma unroll
  for (int mt = 0; mt < MT; ++mt)
    #pragma unroll
    for (int t = 0; t < 8; ++t)
      #pragma unroll
      for (int q = 0; q < 4; ++q) acc[mt][t][q] = 0.f;
  mm_dev<MT>(L, W1, acc, lane);
  epi_ln<MT>(acc, b1, g1, bb1, lane);
  __threadfence_block();
  #pragma unroll
  for (int mt = 0; mt < MT; ++mt)
    #pragma unroll
    for (int t = 0; t < 8; ++t)
      #pragma unroll
      for (int q = 0; q < 4; ++q) {
        const float v = fmaxf(acc[mt][t][q], 0.f);
        stH(L, mt * 16 + 4 * g + q, cr + 16 * t, (_Float16)v);
        acc[mt][t][q] = 0.f;
      }
  __threadfence_block();
  mm_dev<MT>(L, W2, acc, lane);
  epi_ln<MT>(acc, b2, g2, bb2, lane);
  __threadfence_block();
  #pragma unroll
  for (int mt = 0; mt < MT; ++mt)
    #pragma unroll
    for (int t = 0; t < 8; ++t)
      #pragma unroll
      for (int h = 0; h < 2; ++h) {
        const float v0 = fmaxf(acc[mt][t][2 * h + 0] + (float)xres[mt][t][h][0], 0.f);
        const float v1 = fmaxf(acc[mt][t][2 * h + 1] + (float)xres[mt][t][h][1], 0.f);
        if constexpr (MODE <= 1) {
          xres[mt][t][h][0] = (_Float16)v0;
          xres[mt][t][h][1] = (_Float16)v1;
        }
        if constexpr (MODE == 0) {
          stH(L, mt * 16 + 4 * g + 2 * h,     cr + 16 * t, (_Float16)v0);
          stH(L, mt * 16 + 4 * g + 2 * h + 1, cr + 16 * t, (_Float16)v1);
        }
        if constexpr (MODE == 2) {
          gdst[(mt * 16 + 4 * g + 2 * h)     * 128 + cr + 16 * t] = v0;
          gdst[(mt * 16 + 4 * g + 2 * h + 1) * 128 + cr + 16 * t] = v1;
        }
      }
  if constexpr (MODE == 0) __threadfence_block();
}

// ---- K0: pack 8 weight matrices (fp32 [k][n]) into fp16 B-fragment order ----
__global__ __launch_bounds__(256) void k_pack(const float* __restrict__ preW1, const float* __restrict__ preW2,
                                              const float* __restrict__ posW1, const float* __restrict__ posW2,
                                              _Float16* __restrict__ wp) {
  const int o = blockIdx.x * 256 + threadIdx.x;   // 131072 total
  const int mat = o >> 14, rem = o & 16383;
  const int frag = rem >> 9, li = (rem >> 3) & 63, j = rem & 7;
  const int s = frag >> 3, t = frag & 7;
  const int k = s * 32 + ((li >> 4) << 3) + j;
  const int n = t * 16 + (li & 15);
  const int blk = (mat >> 1) & 1, which = mat & 1;
  const float* base;
  if (mat < 4) base = which ? preW2 : preW1;
  else         base = which ? posW2 : posW1;
  wp[o] = (_Float16)base[blk * 16384 + k * 128 + n];
}

// ---- K1: exact 24-NN per point, tie-break = smaller index (matches jax.lax.top_k) ----
__global__ __launch_bounds__(256) void k_knn(const float* __restrict__ xyz, int* __restrict__ idxout) {
  __shared__ float sx[2048], sy[2048], sz[2048];
  const int b = blockIdx.x >> 9;
  const int qbase = (blockIdx.x & 511) * 4;
  const float* xb = xyz + (size_t)b * 2048 * 3;
  for (int i = threadIdx.x; i < 2048; i += 256) {
    sx[i] = xb[i * 3 + 0]; sy[i] = xb[i * 3 + 1]; sz[i] = xb[i * 3 + 2];
  }
  __syncthreads();
  const int lane = threadIdx.x & 63;
  const int q = qbase + (threadIdx.x >> 6);
  const float qx = sx[q], qy = sy[q], qz = sz[q];
  const float q2 = qx * qx + qy * qy + qz * qz;
  float d[32];
  #pragma unroll
  for (int j = 0; j < 32; ++j) {
    const int m = j * 64 + lane;
    const float mx = sx[m], my = sy[m], mz = sz[m];
    const float m2 = mx * mx + my * my + mz * mz;
    d[j] = q2 + m2 - 2.f * (qx * mx + qy * my + qz * mz);
  }
  int keep = 0;
  #pragma unroll 1
  for (int r = 0; r < 24; ++r) {
    float dm = d[0]; int mi = lane;
    #pragma unroll
    for (int j = 1; j < 32; ++j) {
      const bool better = d[j] < dm;       // within a lane, m grows with j -> strict < keeps smallest m on ties
      dm = better ? d[j] : dm;
      mi = better ? (j * 64 + lane) : mi;
    }
    #pragma unroll
    for (int off = 32; off >= 1; off >>= 1) {
      const float od = __shfl_xor(dm, off);
      const int   om = __shfl_xor(mi, off);
      const bool take = (od < dm) || ((od == dm) && (om < mi));
      dm = take ? od : dm;
      mi = take ? om : mi;
    }
    if (lane == r) keep = mi;
    const int tj = (lane == (mi & 63)) ? (mi >> 6) : -1;
    #pragma unroll
    for (int j = 0; j < 32; ++j) d[j] = (j == tj) ? 3.0e38f : d[j];
  }
  if (lane < 24) idxout[(size_t)(b * 2048 + q) * 24 + lane] = keep;
}

// ---- K3: per-wave (2 points, 48 rows): groupnorm+concat build -> 2 pre res_blocks -> max over K ----
__global__ __launch_bounds__(256, 2) void k_pre(
    const float* __restrict__ features, const int* __restrict__ idxin,
    const _Float16* __restrict__ wp, const float* __restrict__ alpha, const float* __restrict__ beta,
    const float* __restrict__ b1, const float* __restrict__ g1, const float* __restrict__ bb1,
    const float* __restrict__ b2, const float* __restrict__ g2, const float* __restrict__ bb2,
    _Float16* __restrict__ h0) {
  __shared__ _Float16 lds[4][48 * 128];
  const int wid = threadIdx.x >> 6, lane = threadIdx.x & 63;
  _Float16* L = lds[wid];
  const int wgl = blockIdx.x * 4 + wid;
  const int p0 = wgl * 2;
  const int b = p0 >> 11;
  const float* fb = features + (size_t)b * 2048 * 64;
  {
    const int c = lane;                       // lane == channel (C=64)
    const float al = alpha[c], be = beta[c];
    #pragma unroll 1
    for (int pp = 0; pp < 2; ++pp) {
      const int p = p0 + pp;
      const int n = p & 2047;
      const int* ip = idxin + (size_t)p * 24;
      const float center = fb[n * 64 + c];
      float v[24]; float su = 0.f, sq = 0.f;
      #pragma unroll
      for (int k = 0; k < 24; ++k) {
        v[k] = fb[ip[k] * 64 + c];
        su += v[k]; sq = fmaf(v[k], v[k], sq);
      }
      const float mean = su * (1.f / 24.f);
      const float var = fmaxf((sq - 24.f * mean * mean) * (1.f / 23.f), 0.f);
      const float rs = 1.f / fmaxf(sqrtf(var), 1e-6f);
      const _Float16 ch = (_Float16)center;
      #pragma unroll
      for (int k = 0; k < 24; ++k) {
        const int row = pp * 24 + k;
        const float nv = (v[k] - mean) * rs * al + be;
        stH(L, row, c, ch);
        stH(L, row, 64 + c, (_Float16)(nv - center));
      }
    }
  }
  __threadfence_block();
  const int g = lane >> 4, cr = lane & 15;
  half2t xres[3][8][2];
  #pragma unroll
  for (int mt = 0; mt < 3; ++mt)
    #pragma unroll
    for (int t = 0; t < 8; ++t)
      #pragma unroll
      for (int h = 0; h < 2; ++h) {
        xres[mt][t][h][0] = ldH(L, mt * 16 + 4 * g + 2 * h,     cr + 16 * t);
        xres[mt][t][h][1] = ldH(L, mt * 16 + 4 * g + 2 * h + 1, cr + 16 * t);
      }
  __threadfence_block();
  res_block_dev<3, 0>(L, wp,         wp + 16384, b1,       g1,       bb1,       b2,       g2,       bb2,       xres, lane, nullptr);
  res_block_dev<3, 1>(L, wp + 32768, wp + 49152, b1 + 128, g1 + 128, bb1 + 128, b2 + 128, g2 + 128, bb2 + 128, xres, lane, nullptr);
  // max over the 24 rows of each point (rows 0..23 -> p0, 24..47 -> p0+1)
  #pragma unroll
  for (int t = 0; t < 8; ++t) {
    float m0 = fmaxf(fmaxf((float)xres[0][t][0][0], (float)xres[0][t][0][1]),
                     fmaxf((float)xres[0][t][1][0], (float)xres[0][t][1][1]));
    m0 = fmaxf(m0, __shfl_xor(m0, 16));
    m0 = fmaxf(m0, __shfl_xor(m0, 32));
    float m1 = fmaxf(fmaxf((float)xres[1][t][0][0], (float)xres[1][t][0][1]),
                     fmaxf((float)xres[1][t][1][0], (float)xres[1][t][1][1]));
    m1 = fmaxf(m1, __shfl_xor(m1, 16));      // lanes g<2: rows16..23 (A); g>=2: rows24..31 (B)
    const float m1o = __shfl_xor(m1, 32);    // lanes g<2 receive B-part
    float m2 = fmaxf(fmaxf((float)xres[2][t][0][0], (float)xres[2][t][0][1]),
                     fmaxf((float)xres[2][t][1][0], (float)xres[2][t][1][1]));
    m2 = fmaxf(m2, __shfl_xor(m2, 16));
    m2 = fmaxf(m2, __shfl_xor(m2, 32));
    const float mA = fmaxf(m0, m1);
    const float mB = fmaxf(m2, m1o);
    if (g == 0) h0[(size_t)p0 * 128 + cr + 16 * t]       = (_Float16)mA;
    if (g == 1) h0[(size_t)(p0 + 1) * 128 + cr + 16 * t] = (_Float16)mB;
  }
}

// ---- K4: pos stage, per-wave 32 rows of h0 -> 2 res_blocks -> h1 (f32) ----
__global__ __launch_bounds__(256, 2) void k_pos(
    const _Float16* __restrict__ h0, const _Float16* __restrict__ wp,
    const float* __restrict__ b1, const float* __restrict__ g1, const float* __restrict__ bb1,
    const float* __restrict__ b2, const float* __restrict__ g2, const float* __restrict__ bb2,
    float* __restrict__ h1) {
  __shared__ _Float16 lds[4][32 * 128];
  const int wid = threadIdx.x >> 6, lane = threadIdx.x & 63;
  _Float16* L = lds[wid];
  const int wgl = blockIdx.x * 4 + wid;
  const size_t rowbase = (size_t)wgl * 32;
  #pragma unroll
  for (int i = 0; i < 8; ++i) {
    const int r = i * 4 + (lane >> 4), ch = lane & 15;
    const half8 tv = *(const half8*)(h0 + (rowbase + r) * 128 + ch * 8);
    *(half8*)((char*)L + r * 256 + ((ch ^ (r & 7)) << 4)) = tv;
  }
  __threadfence_block();
  const int g = lane >> 4, cr = lane & 15;
  half2t xres[2][8][2];
  #pragma unroll
  for (int mt = 0; mt < 2; ++mt)
    #pragma unroll
    for (int t = 0; t < 8; ++t)
      #pragma unroll
      for (int h = 0; h < 2; ++h) {
        xres[mt][t][h][0] = ldH(L, mt * 16 + 4 * g + 2 * h,     cr + 16 * t);
        xres[mt][t][h][1] = ldH(L, mt * 16 + 4 * g + 2 * h + 1, cr + 16 * t);
      }
  __threadfence_block();
  res_block_dev<2, 0>(L, wp + 4 * 16384, wp + 5 * 16384, b1,       g1,       bb1,       b2,       g2,       bb2,       xres, lane, nullptr);
  res_block_dev<2, 2>(L, wp + 6 * 16384, wp + 7 * 16384, b1 + 128, g1 + 128, bb1 + 128, b2 + 128, g2 + 128, bb2 + 128, xres, lane, h1 + rowbase * 128);
}

// ---- K5: gather new_features (h1 by fps_idx) + new_xyz ----
__global__ __launch_bounds__(256) void k_gather(const float* __restrict__ h1, const float* __restrict__ xyz,
                                                const int* __restrict__ fps, float* __restrict__ out) {
  const int i = blockIdx.x * 256 + threadIdx.x;   // grid covers exactly 1048576 + 24576
  if (i < 8 * 1024 * 128) {
    const int c = i & 127, m = (i >> 7) & 1023, b = i >> 17;
    const int n = fps[b * 1024 + m];
    out[i] = h1[((size_t)(b * 2048 + n)) * 128 + c];
  } else {
    const int jj = i - 8 * 1024 * 128;
    if (jj < 8 * 1024 * 3) {
      const int dd = jj % 3, m = (jj / 3) & 1023, b = jj / 3072;
      const int n = fps[b * 1024 + m];
      out[i] = xyz[((size_t)(b * 2048 + n)) * 3 + dd];
    }
  }
}

extern "C" void kernel_launch(void* const* d_in, const int* in_sizes, int n_in,
                              void* d_out, int out_size, void* d_ws, size_t ws_size,
                              hipStream_t stream) {
  const float* features = (const float*)d_in[0];
  const float* xyz      = (const float*)d_in[1];
  const int*   fps      = (const int*)d_in[2];
  const float* alpha    = (const float*)d_in[3];
  const float* beta     = (const float*)d_in[4];
  const float* pre_w1   = (const float*)d_in[5];
  const float* pre_b1   = (const float*)d_in[6];
  const float* pre_g1   = (const float*)d_in[7];
  const float* pre_bb1  = (const float*)d_in[8];
  const float* pre_w2   = (const float*)d_in[9];
  const float* pre_b2   = (const float*)d_in[10];
  const float* pre_g2   = (const float*)d_in[11];
  const float* pre_bb2  = (const float*)d_in[12];
  const float* pos_w1   = (const float*)d_in[13];
  const float* pos_b1   = (const float*)d_in[14];
  const float* pos_g1   = (const float*)d_in[15];
  const float* pos_bb1  = (const float*)d_in[16];
  const float* pos_w2   = (const float*)d_in[17];
  const float* pos_b2   = (const float*)d_in[18];
  const float* pos_g2   = (const float*)d_in[19];
  const float* pos_bb2  = (const float*)d_in[20];
  (void)in_sizes; (void)n_in; (void)out_size; (void)ws_size;

  char* ws = (char*)d_ws;                     // needs ~14.7 MB
  _Float16* wp   = (_Float16*)(ws);           // [0, 262144)
  int*      idxb = (int*)(ws + 262144);       // [262144, 1835008)
  _Float16* h0   = (_Float16*)(ws + 2097152); // [2M, 2M+4M)
  float*    h1   = (float*)(ws + 6291456);    // [6M, 6M+8M)

  k_pack<<<dim3(512), dim3(256), 0, stream>>>(pre_w1, pre_w2, pos_w1, pos_w2, wp);
  k_knn<<<dim3(4096), dim3(256), 0, stream>>>(xyz, idxb);
  k_pre<<<dim3(2048), dim3(256), 0, stream>>>(features, idxb, wp, alpha, beta,
      pre_b1, pre_g1, pre_bb1, pre_b2, pre_g2, pre_bb2, h0);
  k_pos<<<dim3(128), dim3(256), 0, stream>>>(h0, wp,
      pos_b1, pos_g1, pos_bb1, pos_b2, pos_g2, pos_bb2, h1);
  k_gather<<<dim3(4192), dim3(256), 0, stream>>>(h1, xyz, fps, (float*)d_out);
}

// Round 2
// 356.303 us; speedup vs baseline: 1.2433x; 1.2433x over previous
//
#include <hip/hip_runtime.h>

// PointMLP stage: KNN(24) -> groupnorm+concat -> 2x res_block (D=128) -> max over K
//                 -> 2x res_block -> gather by fps_idx.
// fp16 MFMA (16x16x32) for all GEMMs, fp32 for LN/stats/accum.
// B-frag n-mapping: tile t, lane cr -> channel cr*8 + t  (lane's 8 channels contiguous
// -> 16B LDS stores/loads in epilogues).
// ws layout (bytes): wp[0,256K) packed fp16 weights; idx[256K,1.79M); h0[2M,6M) fp16; h1[6M,14.7M) f32.

typedef _Float16 half8  __attribute__((ext_vector_type(8)));
typedef float    f32x4  __attribute__((ext_vector_type(4)));

#define DEVINL __device__ __forceinline__

// ---- swizzled LDS helpers: row stride 256B, XOR 16B-chunk swizzle with (row&7) ----
DEVINL void stH(_Float16* L, int row, int col, _Float16 v) {
  const int b2 = col * 2;
  *(_Float16*)((char*)L + row * 256 + (((b2 >> 4) ^ (row & 7)) << 4) + (b2 & 15)) = v;
}
DEVINL half8 ldA(const _Float16* L, int row, int ch) {
  return *(const half8*)((const char*)L + row * 256 + ((ch ^ (row & 7)) << 4));
}
DEVINL void stA(_Float16* L, int row, int ch, half8 v) {
  *(half8*)((char*)L + row * 256 + ((ch ^ (row & 7)) << 4)) = v;
}

// ---- 48(or 32)x128 @ 128x128 matmul: A from swizzled LDS rows, B(fp16, frag-packed) from global ----
template<int MT>
DEVINL void mm_dev(const _Float16* L, const _Float16* __restrict__ W, f32x4 acc[MT][8], int lane) {
  const int g = lane >> 4, r = lane & 15;
  #pragma unroll
  for (int s = 0; s < 4; ++s) {
    half8 bfr[8];
    #pragma unroll
    for (int t = 0; t < 8; ++t)
      bfr[t] = *(const half8*)(W + (((s * 8 + t) * 64 + lane) * 8));
    #pragma unroll
    for (int mt = 0; mt < MT; ++mt) {
      const half8 a = ldA(L, mt * 16 + r, s * 4 + g);
      #pragma unroll
      for (int t = 0; t < 8; ++t)
        acc[mt][t] = __builtin_amdgcn_mfma_f32_16x16x32_f16(a, bfr[t], acc[mt][t], 0, 0, 0);
    }
  }
}

// ---- bias + LayerNorm(g, bb) applied in-place on D-layout accumulators ----
// channel of acc[mt][t][q] = cr*8 + t ; row = mt*16 + 4*(lane>>4) + q
template<int MT>
DEVINL void epi_ln(f32x4 acc[MT][8], const float* __restrict__ bv, const float* __restrict__ gv,
                   const float* __restrict__ bbv, int lane) {
  const int cr = lane & 15;
  const f32x4 bL = *(const f32x4*)(bv + cr * 8),  bH = *(const f32x4*)(bv + cr * 8 + 4);
  const f32x4 gL = *(const f32x4*)(gv + cr * 8),  gH = *(const f32x4*)(gv + cr * 8 + 4);
  const f32x4 aL = *(const f32x4*)(bbv + cr * 8), aH = *(const f32x4*)(bbv + cr * 8 + 4);
  float su[MT][4], sq[MT][4];
  #pragma unroll
  for (int mt = 0; mt < MT; ++mt)
    #pragma unroll
    for (int q = 0; q < 4; ++q) { su[mt][q] = 0.f; sq[mt][q] = 0.f; }
  #pragma unroll
  for (int mt = 0; mt < MT; ++mt)
    #pragma unroll
    for (int t = 0; t < 8; ++t) {
      const float bias = (t < 4) ? bL[t] : bH[t - 4];
      #pragma unroll
      for (int q = 0; q < 4; ++q) {
        const float x = acc[mt][t][q] + bias;
        acc[mt][t][q] = x;
        su[mt][q] += x;
        sq[mt][q] = fmaf(x, x, sq[mt][q]);
      }
    }
  #pragma unroll
  for (int mask = 1; mask < 16; mask <<= 1) {
    #pragma unroll
    for (int mt = 0; mt < MT; ++mt)
      #pragma unroll
      for (int q = 0; q < 4; ++q) {
        su[mt][q] += __shfl_xor(su[mt][q], mask);
        sq[mt][q] += __shfl_xor(sq[mt][q], mask);
      }
  }
  #pragma unroll
  for (int mt = 0; mt < MT; ++mt)
    #pragma unroll
    for (int q = 0; q < 4; ++q) {
      const float mean = su[mt][q] * (1.f / 128.f);
      const float var  = fmaxf(sq[mt][q] * (1.f / 128.f) - mean * mean, 0.f);
      const float rstd = rsqrtf(var + 1e-5f);
      #pragma unroll
      for (int t = 0; t < 8; ++t) {
        const float gam = (t < 4) ? gL[t] : gH[t - 4];
        const float bet = (t < 4) ? aL[t] : aH[t - 4];
        acc[mt][t][q] = (acc[mt][t][q] - mean) * rstd * gam + bet;
      }
    }
}

// ---- full res_block. xres[mt][q] holds input X row (mt*16+4g+q), 8 channels cr*8.. on entry.
// MODE: 0 = store output rows to LDS (next block reads) + update xres; 1 = update xres only;
//       2 = store f32 rows to gdst.
template<int MT, int MODE>
DEVINL void res_block_dev(_Float16* L, const _Float16* __restrict__ W1, const _Float16* __restrict__ W2,
                          const float* b1, const float* g1, const float* bb1,
                          const float* b2, const float* g2, const float* bb2,
                          half8 xres[MT][4], int lane, float* __restrict__ gdst) {
  const int g = lane >> 4, cr = lane & 15;
  f32x4 acc[MT][8];
  #pragma unroll
  for (int mt = 0; mt < MT; ++mt)
    #pragma unroll
    for (int t = 0; t < 8; ++t)
      #pragma unroll
      for (int q = 0; q < 4; ++q) acc[mt][t][q] = 0.f;
  mm_dev<MT>(L, W1, acc, lane);
  epi_ln<MT>(acc, b1, g1, bb1, lane);
  __threadfence_block();
  #pragma unroll
  for (int mt = 0; mt < MT; ++mt)
    #pragma unroll
    for (int q = 0; q < 4; ++q) {
      half8 hv;
      #pragma unroll
      for (int t = 0; t < 8; ++t) {
        hv[t] = (_Float16)fmaxf(acc[mt][t][q], 0.f);
        acc[mt][t][q] = 0.f;
      }
      const int row = mt * 16 + 4 * g + q;
      stA(L, row, cr, hv);
    }
  __threadfence_block();
  mm_dev<MT>(L, W2, acc, lane);
  epi_ln<MT>(acc, b2, g2, bb2, lane);
  if constexpr (MODE == 0) __threadfence_block();
  #pragma unroll
  for (int mt = 0; mt < MT; ++mt)
    #pragma unroll
    for (int q = 0; q < 4; ++q) {
      const int row = mt * 16 + 4 * g + q;
      float v[8];
      half8 hv;
      #pragma unroll
      for (int t = 0; t < 8; ++t) {
        v[t] = fmaxf(acc[mt][t][q] + (float)xres[mt][q][t], 0.f);
        hv[t] = (_Float16)v[t];
      }
      if constexpr (MODE <= 1) xres[mt][q] = hv;
      if constexpr (MODE == 0) stA(L, row, cr, hv);
      if constexpr (MODE == 2) {
        f32x4 lo, hi;
        #pragma unroll
        for (int e = 0; e < 4; ++e) { lo[e] = v[e]; hi[e] = v[e + 4]; }
        *(f32x4*)(gdst + row * 128 + cr * 8)     = lo;
        *(f32x4*)(gdst + row * 128 + cr * 8 + 4) = hi;
      }
    }
  if constexpr (MODE == 0) __threadfence_block();
}

// ---- K0: pack 8 weight matrices (fp32 [k][n]) into fp16 B-fragment order ----
__global__ __launch_bounds__(256) void k_pack(const float* __restrict__ preW1, const float* __restrict__ preW2,
                                              const float* __restrict__ posW1, const float* __restrict__ posW2,
                                              _Float16* __restrict__ wp) {
  const int o = blockIdx.x * 256 + threadIdx.x;   // 131072 total
  const int mat = o >> 14, rem = o & 16383;
  const int frag = rem >> 9, li = (rem >> 3) & 63, j = rem & 7;
  const int s = frag >> 3, t = frag & 7;
  const int k = s * 32 + ((li >> 4) << 3) + j;
  const int n = (li & 15) * 8 + t;                // channel = cr*8 + t
  const int blk = (mat >> 1) & 1, which = mat & 1;
  const float* base;
  if (mat < 4) base = which ? preW2 : preW1;
  else         base = which ? posW2 : posW1;
  wp[o] = (_Float16)base[blk * 16384 + k * 128 + n];
}

// ---- K1: exact 24-NN per point, tie-break = smaller index (matches jax.lax.top_k) ----
__global__ __launch_bounds__(256) void k_knn(const float* __restrict__ xyz, int* __restrict__ idxout) {
  __shared__ float sx[2048], sy[2048], sz[2048];
  const int b = blockIdx.x >> 9;
  const int qbase = (blockIdx.x & 511) * 4;
  const float* xb = xyz + (size_t)b * 2048 * 3;
  for (int i = threadIdx.x; i < 2048; i += 256) {
    sx[i] = xb[i * 3 + 0]; sy[i] = xb[i * 3 + 1]; sz[i] = xb[i * 3 + 2];
  }
  __syncthreads();
  const int lane = threadIdx.x & 63;
  const int q = qbase + (threadIdx.x >> 6);
  const float qx = sx[q], qy = sy[q], qz = sz[q];
  const float q2 = qx * qx + qy * qy + qz * qz;
  float d[32];
  #pragma unroll
  for (int j = 0; j < 32; ++j) {
    const int m = j * 64 + lane;
    const float mx = sx[m], my = sy[m], mz = sz[m];
    const float m2 = mx * mx + my * my + mz * mz;
    d[j] = q2 + m2 - 2.f * (qx * mx + qy * my + qz * mz);
  }
  int keep = 0;
  #pragma unroll 1
  for (int r = 0; r < 24; ++r) {
    float dm = d[0]; int mi = lane;
    #pragma unroll
    for (int j = 1; j < 32; ++j) {
      const bool better = d[j] < dm;       // within a lane, m grows with j -> strict < keeps smallest m on ties
      dm = better ? d[j] : dm;
      mi = better ? (j * 64 + lane) : mi;
    }
    #pragma unroll
    for (int off = 32; off >= 1; off >>= 1) {
      const float od = __shfl_xor(dm, off);
      const int   om = __shfl_xor(mi, off);
      const bool take = (od < dm) || ((od == dm) && (om < mi));
      dm = take ? od : dm;
      mi = take ? om : mi;
    }
    if (lane == r) keep = mi;
    const int tj = (lane == (mi & 63)) ? (mi >> 6) : -1;
    #pragma unroll
    for (int j = 0; j < 32; ++j) d[j] = (j == tj) ? 3.0e38f : d[j];
  }
  if (lane < 24) idxout[(size_t)(b * 2048 + q) * 24 + lane] = keep;
}

// ---- K3: per-wave (2 points, 48 rows): groupnorm+concat build -> 2 pre res_blocks -> max over K ----
__global__ __launch_bounds__(256, 1) void k_pre(
    const float* __restrict__ features, const int* __restrict__ idxin,
    const _Float16* __restrict__ wp, const float* __restrict__ alpha, const float* __restrict__ beta,
    const float* __restrict__ b1, const float* __restrict__ g1, const float* __restrict__ bb1,
    const float* __restrict__ b2, const float* __restrict__ g2, const float* __restrict__ bb2,
    _Float16* __restrict__ h0) {
  __shared__ _Float16 lds[4][48 * 128];
  const int wid = threadIdx.x >> 6, lane = threadIdx.x & 63;
  _Float16* L = lds[wid];
  const int wgl = blockIdx.x * 4 + wid;
  const int p0 = wgl * 2;
  const int b = p0 >> 11;
  const float* fb = features + (size_t)b * 2048 * 64;
  {
    const int c = lane;                       // lane == channel (C=64)
    const float al = alpha[c], be = beta[c];
    #pragma unroll 1
    for (int pp = 0; pp < 2; ++pp) {
      const int p = p0 + pp;
      const int n = p & 2047;
      const int* ip = idxin + (size_t)p * 24;
      const float center = fb[n * 64 + c];
      float v[24]; float su = 0.f, sq = 0.f;
      #pragma unroll
      for (int k = 0; k < 24; ++k) {
        v[k] = fb[ip[k] * 64 + c];
        su += v[k]; sq = fmaf(v[k], v[k], sq);
      }
      const float mean = su * (1.f / 24.f);
      const float var = fmaxf((sq - 24.f * mean * mean) * (1.f / 23.f), 0.f);
      const float rs = 1.f / fmaxf(sqrtf(var), 1e-6f);
      const _Float16 ch = (_Float16)center;
      #pragma unroll
      for (int k = 0; k < 24; ++k) {
        const int row = pp * 24 + k;
        const float nv = (v[k] - mean) * rs * al + be;
        stH(L, row, c, ch);
        stH(L, row, 64 + c, (_Float16)(nv - center));
      }
    }
  }
  __threadfence_block();
  const int g = lane >> 4, cr = lane & 15;
  half8 xres[3][4];
  #pragma unroll
  for (int mt = 0; mt < 3; ++mt)
    #pragma unroll
    for (int q = 0; q < 4; ++q)
      xres[mt][q] = ldA(L, mt * 16 + 4 * g + q, cr);
  res_block_dev<3, 0>(L, wp,         wp + 16384, b1,       g1,       bb1,       b2,       g2,       bb2,       xres, lane, nullptr);
  res_block_dev<3, 1>(L, wp + 32768, wp + 49152, b1 + 128, g1 + 128, bb1 + 128, b2 + 128, g2 + 128, bb2 + 128, xres, lane, nullptr);
  // max over the 24 rows of each point (rows 0..23 -> p0, 24..47 -> p0+1)
  float mA[8], mB[8];
  #pragma unroll
  for (int t = 0; t < 8; ++t) {
    float m0 = fmaxf(fmaxf((float)xres[0][0][t], (float)xres[0][1][t]),
                     fmaxf((float)xres[0][2][t], (float)xres[0][3][t]));
    m0 = fmaxf(m0, __shfl_xor(m0, 16));
    m0 = fmaxf(m0, __shfl_xor(m0, 32));
    float m1 = fmaxf(fmaxf((float)xres[1][0][t], (float)xres[1][1][t]),
                     fmaxf((float)xres[1][2][t], (float)xres[1][3][t]));
    m1 = fmaxf(m1, __shfl_xor(m1, 16));      // lanes g<2: rows16..23 (A); g>=2: rows24..31 (B)
    const float m1o = __shfl_xor(m1, 32);    // lanes g<2 receive B-part
    float m2 = fmaxf(fmaxf((float)xres[2][0][t], (float)xres[2][1][t]),
                     fmaxf((float)xres[2][2][t], (float)xres[2][3][t]));
    m2 = fmaxf(m2, __shfl_xor(m2, 16));
    m2 = fmaxf(m2, __shfl_xor(m2, 32));
    mA[t] = fmaxf(m0, m1);
    mB[t] = fmaxf(m2, m1o);
  }
  if (g == 0) {
    half8 o;
    #pragma unroll
    for (int t = 0; t < 8; ++t) o[t] = (_Float16)mA[t];
    *(half8*)(h0 + (size_t)p0 * 128 + cr * 8) = o;
  }
  if (g == 1) {
    half8 o;
    #pragma unroll
    for (int t = 0; t < 8; ++t) o[t] = (_Float16)mB[t];
    *(half8*)(h0 + (size_t)(p0 + 1) * 128 + cr * 8) = o;
  }
}

// ---- K4: pos stage, per-wave 32 rows of h0 -> 2 res_blocks -> h1 (f32) ----
__global__ __launch_bounds__(256, 1) void k_pos(
    const _Float16* __restrict__ h0, const _Float16* __restrict__ wp,
    const float* __restrict__ b1, const float* __restrict__ g1, const float* __restrict__ bb1,
    const float* __restrict__ b2, const float* __restrict__ g2, const float* __restrict__ bb2,
    float* __restrict__ h1) {
  __shared__ _Float16 lds[4][32 * 128];
  const int wid = threadIdx.x >> 6, lane = threadIdx.x & 63;
  _Float16* L = lds[wid];
  const int wgl = blockIdx.x * 4 + wid;
  const size_t rowbase = (size_t)wgl * 32;
  #pragma unroll
  for (int i = 0; i < 8; ++i) {
    const int r = i * 4 + (lane >> 4), ch = lane & 15;
    const half8 tv = *(const half8*)(h0 + (rowbase + r) * 128 + ch * 8);
    stA(L, r, ch, tv);
  }
  __threadfence_block();
  const int g = lane >> 4, cr = lane & 15;
  half8 xres[2][4];
  #pragma unroll
  for (int mt = 0; mt < 2; ++mt)
    #pragma unroll
    for (int q = 0; q < 4; ++q)
      xres[mt][q] = ldA(L, mt * 16 + 4 * g + q, cr);
  res_block_dev<2, 0>(L, wp + 4 * 16384, wp + 5 * 16384, b1,       g1,       bb1,       b2,       g2,       bb2,       xres, lane, nullptr);
  res_block_dev<2, 2>(L, wp + 6 * 16384, wp + 7 * 16384, b1 + 128, g1 + 128, bb1 + 128, b2 + 128, g2 + 128, bb2 + 128, xres, lane, h1 + rowbase * 128);
}

// ---- K5: gather new_features (h1 by fps_idx) + new_xyz ----
__global__ __launch_bounds__(256) void k_gather(const float* __restrict__ h1, const float* __restrict__ xyz,
                                                const int* __restrict__ fps, float* __restrict__ out) {
  const int i = blockIdx.x * 256 + threadIdx.x;   // grid covers exactly 1048576 + 24576
  if (i < 8 * 1024 * 128) {
    const int c = i & 127, m = (i >> 7) & 1023, b = i >> 17;
    const int n = fps[b * 1024 + m];
    out[i] = h1[((size_t)(b * 2048 + n)) * 128 + c];
  } else {
    const int jj = i - 8 * 1024 * 128;
    if (jj < 8 * 1024 * 3) {
      const int dd = jj % 3, m = (jj / 3) & 1023, b = jj / 3072;
      const int n = fps[b * 1024 + m];
      out[i] = xyz[((size_t)(b * 2048 + n)) * 3 + dd];
    }
  }
}

extern "C" void kernel_launch(void* const* d_in, const int* in_sizes, int n_in,
                              void* d_out, int out_size, void* d_ws, size_t ws_size,
                              hipStream_t stream) {
  const float* features = (const float*)d_in[0];
  const float* xyz      = (const float*)d_in[1];
  const int*   fps      = (const int*)d_in[2];
  const float* alpha    = (const float*)d_in[3];
  const float* beta     = (const float*)d_in[4];
  const float* pre_w1   = (const float*)d_in[5];
  const float* pre_b1   = (const float*)d_in[6];
  const float* pre_g1   = (const float*)d_in[7];
  const float* pre_bb1  = (const float*)d_in[8];
  const float* pre_w2   = (const float*)d_in[9];
  const float* pre_b2   = (const float*)d_in[10];
  const float* pre_g2   = (const float*)d_in[11];
  const float* pre_bb2  = (const float*)d_in[12];
  const float* pos_w1   = (const float*)d_in[13];
  const float* pos_b1   = (const float*)d_in[14];
  const float* pos_g1   = (const float*)d_in[15];
  const float* pos_bb1  = (const float*)d_in[16];
  const float* pos_w2   = (const float*)d_in[17];
  const float* pos_b2   = (const float*)d_in[18];
  const float* pos_g2   = (const float*)d_in[19];
  const float* pos_bb2  = (const float*)d_in[20];
  (void)in_sizes; (void)n_in; (void)out_size; (void)ws_size;

  char* ws = (char*)d_ws;                     // needs ~14.7 MB
  _Float16* wp   = (_Float16*)(ws);           // [0, 262144)
  int*      idxb = (int*)(ws + 262144);       // [262144, 1835008)
  _Float16* h0   = (_Float16*)(ws + 2097152); // [2M, 2M+4M)
  float*    h1   = (float*)(ws + 6291456);    // [6M, 6M+8M)

  k_pack<<<dim3(512), dim3(256), 0, stream>>>(pre_w1, pre_w2, pos_w1, pos_w2, wp);
  k_knn<<<dim3(4096), dim3(256), 0, stream>>>(xyz, idxb);
  k_pre<<<dim3(2048), dim3(256), 0, stream>>>(features, idxb, wp, alpha, beta,
      pre_b1, pre_g1, pre_bb1, pre_b2, pre_g2, pre_bb2, h0);
  k_pos<<<dim3(128), dim3(256), 0, stream>>>(h0, wp,
      pos_b1, pos_g1, pos_bb1, pos_b2, pos_g2, pos_bb2, h1);
  k_gather<<<dim3(4192), dim3(256), 0, stream>>>(h1, xyz, fps, (float*)d_out);
}

// Round 4
// 272.118 us; speedup vs baseline: 1.6280x; 1.3094x over previous
//
#include <hip/hip_runtime.h>

// PointMLP stage: KNN(24) -> groupnorm+concat -> 2x res_block (D=128) -> max over K
//                 -> 2x res_block -> gather by fps_idx.
// fp16 MFMA (16x16x32); LN stats: mean via 9th MFMA tile (B = rowsum broadcast),
// variance via packed f32 + DPP 16-lane all-reduce (no DS shuffles).
// ws: wp[0,294912) fp16 weights (9 tiles/matrix); idx[512K,2M); h0[2M,6M) f16; h1[6M,14M) f32.

typedef _Float16 half8 __attribute__((ext_vector_type(8)));
typedef _Float16 h2v   __attribute__((ext_vector_type(2)));
typedef float    f32x4 __attribute__((ext_vector_type(4)));

#define DEVINL __device__ __forceinline__

union H8 { half8 v; h2v p[4]; int w[4]; };

DEVINL f32x4 splat4(float s) { f32x4 r = {s, s, s, s}; return r; }

DEVINL _Float16 hmax1(_Float16 a, _Float16 b) { return a > b ? a : b; }
DEVINL h2v hmax2v(h2v a, h2v b) {
  h2v r; r[0] = hmax1(a[0], b[0]); r[1] = hmax1(a[1], b[1]); return r;
}
DEVINL h2v cvt2h(float lo, float hi) {
  return __builtin_bit_cast(h2v, __builtin_amdgcn_cvt_pkrtz(lo, hi));
}
DEVINL half8 hmax8(half8 a, half8 b) {
  H8 A, B, R; A.v = a; B.v = b;
  #pragma unroll
  for (int e = 0; e < 4; ++e) R.p[e] = hmax2v(A.p[e], B.p[e]);
  return R.v;
}
DEVINL half8 shfl_h8(half8 x, int m) {
  H8 X; X.v = x;
  #pragma unroll
  for (int e = 0; e < 4; ++e) X.w[e] = __shfl_xor(X.w[e], m);
  return X.v;
}

// 16-lane (DPP row) all-reduce add: quad xor1, quad xor2, half-mirror, mirror.
DEVINL float dpp_add16(float x) {
  int v = __builtin_bit_cast(int, x);
  x += __builtin_bit_cast(float, __builtin_amdgcn_update_dpp(v, v, 0xB1, 0xF, 0xF, true));
  v = __builtin_bit_cast(int, x);
  x += __builtin_bit_cast(float, __builtin_amdgcn_update_dpp(v, v, 0x4E, 0xF, 0xF, true));
  v = __builtin_bit_cast(int, x);
  x += __builtin_bit_cast(float, __builtin_amdgcn_update_dpp(v, v, 0x141, 0xF, 0xF, true));
  v = __builtin_bit_cast(int, x);
  x += __builtin_bit_cast(float, __builtin_amdgcn_update_dpp(v, v, 0x140, 0xF, 0xF, true));
  return x;
}

// ---- swizzled LDS helpers: row stride 256B, XOR 16B-chunk swizzle with (row&7) ----
DEVINL void stH(_Float16* L, int row, int col, _Float16 v) {
  const int b2 = col * 2;
  *(_Float16*)((char*)L + row * 256 + (((b2 >> 4) ^ (row & 7)) << 4) + (b2 & 15)) = v;
}
DEVINL half8 ldA(const _Float16* L, int row, int ch) {
  return *(const half8*)((const char*)L + row * 256 + ((ch ^ (row & 7)) << 4));
}
DEVINL void stA(_Float16* L, int row, int ch, half8 v) {
  *(half8*)((char*)L + row * 256 + ((ch ^ (row & 7)) << 4)) = v;
}

// ---- A(from LDS) @ B(9-tile frag-packed W): tiles 0..7 = outputs, tile 8 = rowsum ----
template<int MT>
DEVINL void mm_dev(const _Float16* L, const _Float16* __restrict__ W, f32x4 acc[MT][9], int lane) {
  const int g = lane >> 4, r = lane & 15;
  #pragma unroll
  for (int s = 0; s < 4; ++s) {
    half8 bfr[9];
    #pragma unroll
    for (int t = 0; t < 9; ++t)
      bfr[t] = *(const half8*)(W + (((s * 9 + t) * 64 + lane) * 8));
    #pragma unroll
    for (int mt = 0; mt < MT; ++mt) {
      const half8 a = ldA(L, mt * 16 + r, s * 4 + g);
      #pragma unroll
      for (int t = 0; t < 9; ++t)
        acc[mt][t] = __builtin_amdgcn_mfma_f32_16x16x32_f16(a, bfr[t], acc[mt][t], 0, 0, 0);
    }
  }
}

// ---- bias + LayerNorm; mean from acc[mt][8] (MFMA rowsum) + sum(bias); var via DPP reduce ----
template<int MT>
DEVINL void epi_ln(f32x4 acc[MT][9], const float* __restrict__ bv, const float* __restrict__ gv,
                   const float* __restrict__ bbv, int lane) {
  const int cr = lane & 15;
  const f32x4 bp0 = *(const f32x4*)(bv + cr * 8),  bp1 = *(const f32x4*)(bv + cr * 8 + 4);
  const f32x4 gp0 = *(const f32x4*)(gv + cr * 8),  gp1 = *(const f32x4*)(gv + cr * 8 + 4);
  const f32x4 ap0 = *(const f32x4*)(bbv + cr * 8), ap1 = *(const f32x4*)(bbv + cr * 8 + 4);
  // sum of all 128 biases (scalar, shared by all rows)
  const f32x4 bs4 = bp0 + bp1;
  const float sb = dpp_add16(bs4[0] + bs4[1] + bs4[2] + bs4[3]);
  #pragma unroll
  for (int mt = 0; mt < MT; ++mt) {
    f32x4 sq4 = splat4(0.f);
    #pragma unroll
    for (int t = 0; t < 8; ++t) {
      const float bias = (t < 4) ? bp0[t & 3] : bp1[t & 3];
      acc[mt][t] = acc[mt][t] + splat4(bias);
      sq4 = sq4 + acc[mt][t] * acc[mt][t];
    }
    #pragma unroll
    for (int q = 0; q < 4; ++q) sq4[q] = dpp_add16(sq4[q]);
    const f32x4 mean = (acc[mt][8] + splat4(sb)) * splat4(1.f / 128.f);
    f32x4 rstd;
    #pragma unroll
    for (int q = 0; q < 4; ++q) {
      const float var = fmaxf(sq4[q] * (1.f / 128.f) - mean[q] * mean[q], 0.f);
      rstd[q] = rsqrtf(var + 1e-5f);
    }
    #pragma unroll
    for (int t = 0; t < 8; ++t) {
      const float gs = (t < 4) ? gp0[t & 3] : gp1[t & 3];
      const float as = (t < 4) ? ap0[t & 3] : ap1[t & 3];
      acc[mt][t] = (acc[mt][t] - mean) * rstd * splat4(gs) + splat4(as);
    }
  }
}

// ---- full res_block. xres[mt][q]: input X row (mt*16+4g+q), channels cr*8.. (f16).
// MODE: 0 = store out rows to LDS + update xres; 1 = update xres only; 2 = f32 rows to gdst.
template<int MT, int MODE>
DEVINL void res_block_dev(_Float16* L, const _Float16* __restrict__ W1, const _Float16* __restrict__ W2,
                          const float* b1, const float* g1, const float* bb1,
                          const float* b2, const float* g2, const float* bb2,
                          half8 xres[MT][4], int lane, float* __restrict__ gdst) {
  const int g = lane >> 4, cr = lane & 15;
  const h2v zero2 = {(_Float16)0, (_Float16)0};
  f32x4 acc[MT][9];
  #pragma unroll
  for (int mt = 0; mt < MT; ++mt)
    #pragma unroll
    for (int t = 0; t < 9; ++t) acc[mt][t] = splat4(0.f);
  mm_dev<MT>(L, W1, acc, lane);
  epi_ln<MT>(acc, b1, g1, bb1, lane);
  __threadfence_block();
  #pragma unroll
  for (int mt = 0; mt < MT; ++mt)
    #pragma unroll
    for (int q = 0; q < 4; ++q) {
      H8 hv;
      #pragma unroll
      for (int e = 0; e < 4; ++e)
        hv.p[e] = hmax2v(cvt2h(acc[mt][2 * e][q], acc[mt][2 * e + 1][q]), zero2);
      stA(L, mt * 16 + 4 * g + q, cr, hv.v);
    }
  #pragma unroll
  for (int mt = 0; mt < MT; ++mt)
    #pragma unroll
    for (int t = 0; t < 9; ++t) acc[mt][t] = splat4(0.f);
  __threadfence_block();
  mm_dev<MT>(L, W2, acc, lane);
  epi_ln<MT>(acc, b2, g2, bb2, lane);
  if constexpr (MODE == 0) __threadfence_block();
  #pragma unroll
  for (int mt = 0; mt < MT; ++mt)
    #pragma unroll
    for (int q = 0; q < 4; ++q) {
      const int row = mt * 16 + 4 * g + q;
      if constexpr (MODE == 2) {
        f32x4 lo, hi;
        #pragma unroll
        for (int e = 0; e < 4; ++e) {
          lo[e] = fmaxf(acc[mt][e][q]     + (float)xres[mt][q][e],     0.f);
          hi[e] = fmaxf(acc[mt][e + 4][q] + (float)xres[mt][q][e + 4], 0.f);
        }
        *(f32x4*)(gdst + row * 128 + cr * 8)     = lo;
        *(f32x4*)(gdst + row * 128 + cr * 8 + 4) = hi;
      } else {
        H8 s;
        #pragma unroll
        for (int e = 0; e < 4; ++e)
          s.p[e] = cvt2h(acc[mt][2 * e][q], acc[mt][2 * e + 1][q]);
        H8 z; z.v = s.v + xres[mt][q];
        #pragma unroll
        for (int e = 0; e < 4; ++e) z.p[e] = hmax2v(z.p[e], zero2);
        xres[mt][q] = z.v;
        if constexpr (MODE == 0) stA(L, row, cr, z.v);
      }
    }
  if constexpr (MODE == 0) __threadfence_block();
}

// ---- K0: pack 8 weight matrices into 9-tile fp16 B-fragment order (tile 8 = rowsum bcast) ----
__global__ __launch_bounds__(256) void k_pack(const float* __restrict__ preW1, const float* __restrict__ preW2,
                                              const float* __restrict__ posW1, const float* __restrict__ posW2,
                                              _Float16* __restrict__ wp) {
  const int o = blockIdx.x * 256 + threadIdx.x;   // 147456 total (576 blocks)
  const int mat = o / 18432, rem = o % 18432;
  const int frag = rem >> 9, li = (rem >> 3) & 63, j = rem & 7;
  const int s = frag / 9, t = frag % 9;
  const int k = s * 32 + ((li >> 4) << 3) + j;
  const int blk = (mat >> 1) & 1, which = mat & 1;
  const float* base = (mat < 4) ? (which ? preW2 : preW1) : (which ? posW2 : posW1);
  const float* Wm = base + blk * 16384;
  float val;
  if (t < 8) {
    val = Wm[k * 128 + (li & 15) * 8 + t];
  } else {
    float ssum = 0.f;
    for (int n = 0; n < 128; ++n) ssum += Wm[k * 128 + n];
    val = ssum;
  }
  wp[o] = (_Float16)val;
}

// ---- K1: exact 24-NN per point, tie-break = smaller index (matches jax.lax.top_k) ----
__global__ __launch_bounds__(256) void k_knn(const float* __restrict__ xyz, int* __restrict__ idxout) {
  __shared__ float sx[2048], sy[2048], sz[2048];
  const int b = blockIdx.x >> 9;
  const int qbase = (blockIdx.x & 511) * 4;
  const float* xb = xyz + (size_t)b * 2048 * 3;
  for (int i = threadIdx.x; i < 2048; i += 256) {
    sx[i] = xb[i * 3 + 0]; sy[i] = xb[i * 3 + 1]; sz[i] = xb[i * 3 + 2];
  }
  __syncthreads();
  const int lane = threadIdx.x & 63;
  const int q = qbase + (threadIdx.x >> 6);
  const float qx = sx[q], qy = sy[q], qz = sz[q];
  const float q2 = qx * qx + qy * qy + qz * qz;
  float d[32];
  #pragma unroll
  for (int j = 0; j < 32; ++j) {
    const int m = j * 64 + lane;
    const float mx = sx[m], my = sy[m], mz = sz[m];
    const float m2 = mx * mx + my * my + mz * mz;
    d[j] = q2 + m2 - 2.f * (qx * mx + qy * my + qz * mz);
  }
  int keep = 0;
  #pragma unroll 1
  for (int r = 0; r < 24; ++r) {
    float dm = d[0]; int mi = lane;
    #pragma unroll
    for (int j = 1; j < 32; ++j) {
      const bool better = d[j] < dm;
      dm = better ? d[j] : dm;
      mi = better ? (j * 64 + lane) : mi;
    }
    #pragma unroll
    for (int off = 32; off >= 1; off >>= 1) {
      const float od = __shfl_xor(dm, off);
      const int   om = __shfl_xor(mi, off);
      const bool take = (od < dm) || ((od == dm) && (om < mi));
      dm = take ? od : dm;
      mi = take ? om : mi;
    }
    if (lane == r) keep = mi;
    const int tj = (lane == (mi & 63)) ? (mi >> 6) : -1;
    #pragma unroll
    for (int j = 0; j < 32; ++j) d[j] = (j == tj) ? 3.0e38f : d[j];
  }
  if (lane < 24) idxout[(size_t)(b * 2048 + q) * 24 + lane] = keep;
}

// ---- K3: per-wave (2 points, 48 rows): groupnorm+concat -> 2 pre res_blocks -> max over K ----
__global__ __launch_bounds__(256, 2) void k_pre(
    const float* __restrict__ features, const int* __restrict__ idxin,
    const _Float16* __restrict__ wp, const float* __restrict__ alpha, const float* __restrict__ beta,
    const float* __restrict__ b1, const float* __restrict__ g1, const float* __restrict__ bb1,
    const float* __restrict__ b2, const float* __restrict__ g2, const float* __restrict__ bb2,
    _Float16* __restrict__ h0) {
  __shared__ _Float16 lds[4][48 * 128];
  const int wid = threadIdx.x >> 6, lane = threadIdx.x & 63;
  _Float16* L = lds[wid];
  const int wgl = blockIdx.x * 4 + wid;
  const int p0 = wgl * 2;
  const int b = p0 >> 11;
  const float* fb = features + (size_t)b * 2048 * 64;
  {
    const int c = lane;
    const float al = alpha[c], be = beta[c];
    #pragma unroll 1
    for (int pp = 0; pp < 2; ++pp) {
      const int p = p0 + pp;
      const int n = p & 2047;
      const int* ip = idxin + (size_t)p * 24;
      const float center = fb[n * 64 + c];
      float v[24]; float su = 0.f, sq = 0.f;
      #pragma unroll
      for (int k = 0; k < 24; ++k) {
        v[k] = fb[ip[k] * 64 + c];
        su += v[k]; sq = fmaf(v[k], v[k], sq);
      }
      const float mean = su * (1.f / 24.f);
      const float var = fmaxf((sq - 24.f * mean * mean) * (1.f / 23.f), 0.f);
      const float rs = 1.f / fmaxf(sqrtf(var), 1e-6f);
      const float c1 = rs * al;
      const float c0 = be - mean * c1 - center;
      const _Float16 ch = (_Float16)center;
      #pragma unroll
      for (int k = 0; k < 24; ++k) {
        const int row = pp * 24 + k;
        stH(L, row, c, ch);
        stH(L, row, 64 + c, (_Float16)fmaf(v[k], c1, c0));
      }
    }
  }
  __threadfence_block();
  const int g = lane >> 4, cr = lane & 15;
  half8 xres[3][4];
  #pragma unroll
  for (int mt = 0; mt < 3; ++mt)
    #pragma unroll
    for (int q = 0; q < 4; ++q)
      xres[mt][q] = ldA(L, mt * 16 + 4 * g + q, cr);
  res_block_dev<3, 0>(L, wp,         wp + 18432,  b1,       g1,       bb1,       b2,       g2,       bb2,       xres, lane, nullptr);
  res_block_dev<3, 1>(L, wp + 36864, wp + 55296,  b1 + 128, g1 + 128, bb1 + 128, b2 + 128, g2 + 128, bb2 + 128, xres, lane, nullptr);
  // max over the 24 rows of each point (rows 0..23 -> p0, 24..47 -> p0+1), all in f16
  half8 m0 = hmax8(hmax8(xres[0][0], xres[0][1]), hmax8(xres[0][2], xres[0][3]));
  m0 = hmax8(m0, shfl_h8(m0, 16));
  m0 = hmax8(m0, shfl_h8(m0, 32));
  half8 m1 = hmax8(hmax8(xres[1][0], xres[1][1]), hmax8(xres[1][2], xres[1][3]));
  m1 = hmax8(m1, shfl_h8(m1, 16));          // g0/g1 hold rows16..23 (p0); g2/g3 rows24..31 (p1)
  const half8 m1o = shfl_h8(m1, 32);        // bring p1-part to g0/g1 side
  half8 m2 = hmax8(hmax8(xres[2][0], xres[2][1]), hmax8(xres[2][2], xres[2][3]));
  m2 = hmax8(m2, shfl_h8(m2, 16));
  m2 = hmax8(m2, shfl_h8(m2, 32));
  if (g == 0) *(half8*)(h0 + (size_t)p0 * 128 + cr * 8)       = hmax8(m0, m1);
  if (g == 1) *(half8*)(h0 + (size_t)(p0 + 1) * 128 + cr * 8) = hmax8(m2, m1o);
}

// ---- K4: pos stage, per-wave 32 rows of h0 -> 2 res_blocks -> h1 (f32) ----
__global__ __launch_bounds__(128, 2) void k_pos(
    const _Float16* __restrict__ h0, const _Float16* __restrict__ wp,
    const float* __restrict__ b1, const float* __restrict__ g1, const float* __restrict__ bb1,
    const float* __restrict__ b2, const float* __restrict__ g2, const float* __restrict__ bb2,
    float* __restrict__ h1) {
  __shared__ _Float16 lds[2][32 * 128];
  const int wid = threadIdx.x >> 6, lane = threadIdx.x & 63;
  _Float16* L = lds[wid];
  const int wgl = blockIdx.x * 2 + wid;
  const size_t rowbase = (size_t)wgl * 32;
  #pragma unroll
  for (int i = 0; i < 8; ++i) {
    const int r = i * 4 + (lane >> 4), ch = lane & 15;
    const half8 tv = *(const half8*)(h0 + (rowbase + r) * 128 + ch * 8);
    stA(L, r, ch, tv);
  }
  __threadfence_block();
  const int g = lane >> 4, cr = lane & 15;
  half8 xres[2][4];
  #pragma unroll
  for (int mt = 0; mt < 2; ++mt)
    #pragma unroll
    for (int q = 0; q < 4; ++q)
      xres[mt][q] = ldA(L, mt * 16 + 4 * g + q, cr);
  res_block_dev<2, 0>(L, wp + 73728,  wp + 92160,  b1,       g1,       bb1,       b2,       g2,       bb2,       xres, lane, nullptr);
  res_block_dev<2, 2>(L, wp + 110592, wp + 129024, b1 + 128, g1 + 128, bb1 + 128, b2 + 128, g2 + 128, bb2 + 128, xres, lane, h1 + rowbase * 128);
}

// ---- K5: gather new_features (h1 by fps_idx, float4) + new_xyz ----
__global__ __launch_bounds__(256) void k_gather(const float* __restrict__ h1, const float* __restrict__ xyz,
                                                const int* __restrict__ fps, float* __restrict__ out) {
  const int i = blockIdx.x * 256 + threadIdx.x;
  const int FEAT4 = 8 * 1024 * 32;   // 262144 float4 elements
  if (i < FEAT4) {
    const int c4 = i & 31, m = (i >> 5) & 1023, b = i >> 15;
    const int n = fps[b * 1024 + m];
    const f32x4 v = *(const f32x4*)(h1 + ((size_t)(b * 2048 + n)) * 128 + c4 * 4);
    *(f32x4*)(out + (size_t)i * 4) = v;
  } else {
    const int jj = i - FEAT4;
    if (jj < 8 * 1024 * 3) {
      const int dd = jj % 3, m = (jj / 3) & 1023, b = jj / 3072;
      const int n = fps[b * 1024 + m];
      out[8 * 1024 * 128 + jj] = xyz[((size_t)(b * 2048 + n)) * 3 + dd];
    }
  }
}

extern "C" void kernel_launch(void* const* d_in, const int* in_sizes, int n_in,
                              void* d_out, int out_size, void* d_ws, size_t ws_size,
                              hipStream_t stream) {
  const float* features = (const float*)d_in[0];
  const float* xyz      = (const float*)d_in[1];
  const int*   fps      = (const int*)d_in[2];
  const float* alpha    = (const float*)d_in[3];
  const float* beta     = (const float*)d_in[4];
  const float* pre_w1   = (const float*)d_in[5];
  const float* pre_b1   = (const float*)d_in[6];
  const float* pre_g1   = (const float*)d_in[7];
  const float* pre_bb1  = (const float*)d_in[8];
  const float* pre_w2   = (const float*)d_in[9];
  const float* pre_b2   = (const float*)d_in[10];
  const float* pre_g2   = (const float*)d_in[11];
  const float* pre_bb2  = (const float*)d_in[12];
  const float* pos_w1   = (const float*)d_in[13];
  const float* pos_b1   = (const float*)d_in[14];
  const float* pos_g1   = (const float*)d_in[15];
  const float* pos_bb1  = (const float*)d_in[16];
  const float* pos_w2   = (const float*)d_in[17];
  const float* pos_b2   = (const float*)d_in[18];
  const float* pos_g2   = (const float*)d_in[19];
  const float* pos_bb2  = (const float*)d_in[20];
  (void)in_sizes; (void)n_in; (void)out_size; (void)ws_size;

  char* ws = (char*)d_ws;                     // needs ~14.3 MB
  _Float16* wp   = (_Float16*)(ws);           // [0, 294912)
  int*      idxb = (int*)(ws + 524288);       // [512K, 2M)
  _Float16* h0   = (_Float16*)(ws + 2097152); // [2M, 6M)
  float*    h1   = (float*)(ws + 6291456);    // [6M, 14M)

  k_pack<<<dim3(576), dim3(256), 0, stream>>>(pre_w1, pre_w2, pos_w1, pos_w2, wp);
  k_knn<<<dim3(4096), dim3(256), 0, stream>>>(xyz, idxb);
  k_pre<<<dim3(2048), dim3(256), 0, stream>>>(features, idxb, wp, alpha, beta,
      pre_b1, pre_g1, pre_bb1, pre_b2, pre_g2, pre_bb2, h0);
  k_pos<<<dim3(256), dim3(128), 0, stream>>>(h0, wp,
      pos_b1, pos_g1, pos_bb1, pos_b2, pos_g2, pos_bb2, h1);
  k_gather<<<dim3(1120), dim3(256), 0, stream>>>(h1, xyz, fps, (float*)d_out);
}

// Round 5
// 241.324 us; speedup vs baseline: 1.8357x; 1.1276x over previous
//
#include <hip/hip_runtime.h>

// PointMLP stage: KNN(24) -> groupnorm+concat -> 2x res_block (D=128) -> max over K
//                 -> 2x res_block -> gather by fps_idx.
// fp16 MFMA (16x16x32); LN stats: mean via 9th MFMA tile (B = rowsum broadcast),
// variance via packed f32 + DPP 16-lane all-reduce (no DS shuffles).
// KNN: u64 keys (dist_bits<<32 | idx), 4x8 grouped tournament, winning-lane-only
// invalidation+regroup under divergent branch.
// ws: wp[0,294912) fp16 weights (9 tiles/matrix); idx[512K,2M); h0[2M,6M) f16; h1[6M,14M) f32.

typedef _Float16 half8 __attribute__((ext_vector_type(8)));
typedef _Float16 h2v   __attribute__((ext_vector_type(2)));
typedef float    f32x4 __attribute__((ext_vector_type(4)));
typedef unsigned long long u64;

#define DEVINL __device__ __forceinline__

union H8 { half8 v; h2v p[4]; int w[4]; };

DEVINL f32x4 splat4(float s) { f32x4 r = {s, s, s, s}; return r; }

DEVINL _Float16 hmax1(_Float16 a, _Float16 b) { return a > b ? a : b; }
DEVINL h2v hmax2v(h2v a, h2v b) {
  h2v r; r[0] = hmax1(a[0], b[0]); r[1] = hmax1(a[1], b[1]); return r;
}
DEVINL h2v cvt2h(float lo, float hi) {
  return __builtin_bit_cast(h2v, __builtin_amdgcn_cvt_pkrtz(lo, hi));
}
DEVINL half8 hmax8(half8 a, half8 b) {
  H8 A, B, R; A.v = a; B.v = b;
  #pragma unroll
  for (int e = 0; e < 4; ++e) R.p[e] = hmax2v(A.p[e], B.p[e]);
  return R.v;
}
DEVINL half8 shfl_h8(half8 x, int m) {
  H8 X; X.v = x;
  #pragma unroll
  for (int e = 0; e < 4; ++e) X.w[e] = __shfl_xor(X.w[e], m);
  return X.v;
}

// 16-lane (DPP row) all-reduce add: quad xor1, quad xor2, half-mirror, mirror.
DEVINL float dpp_add16(float x) {
  int v = __builtin_bit_cast(int, x);
  x += __builtin_bit_cast(float, __builtin_amdgcn_update_dpp(v, v, 0xB1, 0xF, 0xF, true));
  v = __builtin_bit_cast(int, x);
  x += __builtin_bit_cast(float, __builtin_amdgcn_update_dpp(v, v, 0x4E, 0xF, 0xF, true));
  v = __builtin_bit_cast(int, x);
  x += __builtin_bit_cast(float, __builtin_amdgcn_update_dpp(v, v, 0x141, 0xF, 0xF, true));
  v = __builtin_bit_cast(int, x);
  x += __builtin_bit_cast(float, __builtin_amdgcn_update_dpp(v, v, 0x140, 0xF, 0xF, true));
  return x;
}

// ---- swizzled LDS helpers: row stride 256B, XOR 16B-chunk swizzle with (row&7) ----
DEVINL void stH(_Float16* L, int row, int col, _Float16 v) {
  const int b2 = col * 2;
  *(_Float16*)((char*)L + row * 256 + (((b2 >> 4) ^ (row & 7)) << 4) + (b2 & 15)) = v;
}
DEVINL half8 ldA(const _Float16* L, int row, int ch) {
  return *(const half8*)((const char*)L + row * 256 + ((ch ^ (row & 7)) << 4));
}
DEVINL void stA(_Float16* L, int row, int ch, half8 v) {
  *(half8*)((char*)L + row * 256 + ((ch ^ (row & 7)) << 4)) = v;
}

// ---- A(from LDS) @ B(9-tile frag-packed W): tiles 0..7 = outputs, tile 8 = rowsum ----
template<int MT>
DEVINL void mm_dev(const _Float16* L, const _Float16* __restrict__ W, f32x4 acc[MT][9], int lane) {
  const int g = lane >> 4, r = lane & 15;
  #pragma unroll
  for (int s = 0; s < 4; ++s) {
    half8 bfr[9];
    #pragma unroll
    for (int t = 0; t < 9; ++t)
      bfr[t] = *(const half8*)(W + (((s * 9 + t) * 64 + lane) * 8));
    #pragma unroll
    for (int mt = 0; mt < MT; ++mt) {
      const half8 a = ldA(L, mt * 16 + r, s * 4 + g);
      #pragma unroll
      for (int t = 0; t < 9; ++t)
        acc[mt][t] = __builtin_amdgcn_mfma_f32_16x16x32_f16(a, bfr[t], acc[mt][t], 0, 0, 0);
    }
  }
}

// ---- bias + LayerNorm; mean from acc[mt][8] (MFMA rowsum) + sum(bias); var via DPP reduce ----
template<int MT>
DEVINL void epi_ln(f32x4 acc[MT][9], const float* __restrict__ bv, const float* __restrict__ gv,
                   const float* __restrict__ bbv, int lane) {
  const int cr = lane & 15;
  const f32x4 bp0 = *(const f32x4*)(bv + cr * 8),  bp1 = *(const f32x4*)(bv + cr * 8 + 4);
  const f32x4 gp0 = *(const f32x4*)(gv + cr * 8),  gp1 = *(const f32x4*)(gv + cr * 8 + 4);
  const f32x4 ap0 = *(const f32x4*)(bbv + cr * 8), ap1 = *(const f32x4*)(bbv + cr * 8 + 4);
  const f32x4 bs4 = bp0 + bp1;
  const float sb = dpp_add16(bs4[0] + bs4[1] + bs4[2] + bs4[3]);
  #pragma unroll
  for (int mt = 0; mt < MT; ++mt) {
    f32x4 sq4 = splat4(0.f);
    #pragma unroll
    for (int t = 0; t < 8; ++t) {
      const float bias = (t < 4) ? bp0[t & 3] : bp1[t & 3];
      acc[mt][t] = acc[mt][t] + splat4(bias);
      sq4 = sq4 + acc[mt][t] * acc[mt][t];
    }
    #pragma unroll
    for (int q = 0; q < 4; ++q) sq4[q] = dpp_add16(sq4[q]);
    const f32x4 mean = (acc[mt][8] + splat4(sb)) * splat4(1.f / 128.f);
    f32x4 rstd;
    #pragma unroll
    for (int q = 0; q < 4; ++q) {
      const float var = fmaxf(sq4[q] * (1.f / 128.f) - mean[q] * mean[q], 0.f);
      rstd[q] = rsqrtf(var + 1e-5f);
    }
    #pragma unroll
    for (int t = 0; t < 8; ++t) {
      const float gs = (t < 4) ? gp0[t & 3] : gp1[t & 3];
      const float as = (t < 4) ? ap0[t & 3] : ap1[t & 3];
      acc[mt][t] = (acc[mt][t] - mean) * rstd * splat4(gs) + splat4(as);
    }
  }
}

// ---- full res_block. xres[mt][q]: input X row (mt*16+4g+q), channels cr*8.. (f16).
// MODE: 0 = store out rows to LDS + update xres; 1 = update xres only; 2 = f32 rows to gdst.
template<int MT, int MODE>
DEVINL void res_block_dev(_Float16* L, const _Float16* __restrict__ W1, const _Float16* __restrict__ W2,
                          const float* b1, const float* g1, const float* bb1,
                          const float* b2, const float* g2, const float* bb2,
                          half8 xres[MT][4], int lane, float* __restrict__ gdst) {
  const int g = lane >> 4, cr = lane & 15;
  const h2v zero2 = {(_Float16)0, (_Float16)0};
  f32x4 acc[MT][9];
  #pragma unroll
  for (int mt = 0; mt < MT; ++mt)
    #pragma unroll
    for (int t = 0; t < 9; ++t) acc[mt][t] = splat4(0.f);
  mm_dev<MT>(L, W1, acc, lane);
  epi_ln<MT>(acc, b1, g1, bb1, lane);
  __threadfence_block();
  #pragma unroll
  for (int mt = 0; mt < MT; ++mt)
    #pragma unroll
    for (int q = 0; q < 4; ++q) {
      H8 hv;
      #pragma unroll
      for (int e = 0; e < 4; ++e)
        hv.p[e] = hmax2v(cvt2h(acc[mt][2 * e][q], acc[mt][2 * e + 1][q]), zero2);
      stA(L, mt * 16 + 4 * g + q, cr, hv.v);
    }
  #pragma unroll
  for (int mt = 0; mt < MT; ++mt)
    #pragma unroll
    for (int t = 0; t < 9; ++t) acc[mt][t] = splat4(0.f);
  __threadfence_block();
  mm_dev<MT>(L, W2, acc, lane);
  epi_ln<MT>(acc, b2, g2, bb2, lane);
  if constexpr (MODE == 0) __threadfence_block();
  #pragma unroll
  for (int mt = 0; mt < MT; ++mt)
    #pragma unroll
    for (int q = 0; q < 4; ++q) {
      const int row = mt * 16 + 4 * g + q;
      if constexpr (MODE == 2) {
        f32x4 lo, hi;
        #pragma unroll
        for (int e = 0; e < 4; ++e) {
          lo[e] = fmaxf(acc[mt][e][q]     + (float)xres[mt][q][e],     0.f);
          hi[e] = fmaxf(acc[mt][e + 4][q] + (float)xres[mt][q][e + 4], 0.f);
        }
        *(f32x4*)(gdst + row * 128 + cr * 8)     = lo;
        *(f32x4*)(gdst + row * 128 + cr * 8 + 4) = hi;
      } else {
        H8 s;
        #pragma unroll
        for (int e = 0; e < 4; ++e)
          s.p[e] = cvt2h(acc[mt][2 * e][q], acc[mt][2 * e + 1][q]);
        H8 z; z.v = s.v + xres[mt][q];
        #pragma unroll
        for (int e = 0; e < 4; ++e) z.p[e] = hmax2v(z.p[e], zero2);
        xres[mt][q] = z.v;
        if constexpr (MODE == 0) stA(L, row, cr, z.v);
      }
    }
  if constexpr (MODE == 0) __threadfence_block();
}

// ---- K0: pack 8 weight matrices into 9-tile fp16 B-fragment order (tile 8 = rowsum bcast) ----
__global__ __launch_bounds__(256) void k_pack(const float* __restrict__ preW1, const float* __restrict__ preW2,
                                              const float* __restrict__ posW1, const float* __restrict__ posW2,
                                              _Float16* __restrict__ wp) {
  const int o = blockIdx.x * 256 + threadIdx.x;   // 147456 total (576 blocks)
  const int mat = o / 18432, rem = o % 18432;
  const int frag = rem >> 9, li = (rem >> 3) & 63, j = rem & 7;
  const int s = frag / 9, t = frag % 9;
  const int k = s * 32 + ((li >> 4) << 3) + j;
  const int blk = (mat >> 1) & 1, which = mat & 1;
  const float* base = (mat < 4) ? (which ? preW2 : preW1) : (which ? posW2 : posW1);
  const float* Wm = base + blk * 16384;
  float val;
  if (t < 8) {
    val = Wm[k * 128 + (li & 15) * 8 + t];
  } else {
    float ssum = 0.f;
    for (int n = 0; n < 128; ++n) ssum += Wm[k * 128 + n];
    val = ssum;
  }
  wp[o] = (_Float16)val;
}

// ---- KNN helpers: u64 key = (f32bits(d) << 32) | m  (d >= 0) ----
DEVINL u64 kmin(u64 a, u64 b) { return a < b ? a : b; }
DEVINL u64 min8(const u64* k) {
  u64 a = kmin(k[0], k[1]), b = kmin(k[2], k[3]);
  u64 c = kmin(k[4], k[5]), d = kmin(k[6], k[7]);
  return kmin(kmin(a, b), kmin(c, d));
}
DEVINL void inv8(u64* k, int j) {
  #pragma unroll
  for (int s = 0; s < 8; ++s) k[s] = (s == j) ? ~0ULL : k[s];
}

// ---- K1: exact 24-NN per point, tie-break = smaller index (u64 lex order) ----
__global__ __launch_bounds__(256) void k_knn(const float* __restrict__ xyz, int* __restrict__ idxout) {
  __shared__ float sx[2048], sy[2048], sz[2048];
  const int b = blockIdx.x >> 9;
  const int qbase = (blockIdx.x & 511) * 4;
  const float* xb = xyz + (size_t)b * 2048 * 3;
  for (int i = threadIdx.x; i < 2048; i += 256) {
    sx[i] = xb[i * 3 + 0]; sy[i] = xb[i * 3 + 1]; sz[i] = xb[i * 3 + 2];
  }
  __syncthreads();
  const int lane = threadIdx.x & 63;
  const int q = qbase + (threadIdx.x >> 6);
  const float qx = sx[q], qy = sy[q], qz = sz[q];
  const float q2 = qx * qx + qy * qy + qz * qz;
  u64 key[32];
  #pragma unroll
  for (int j = 0; j < 32; ++j) {
    const int m = j * 64 + lane;
    const float mx = sx[m], my = sy[m], mz = sz[m];
    const float m2 = mx * mx + my * my + mz * mz;
    const float d = fmaxf(q2 + m2 - 2.f * (qx * mx + qy * my + qz * mz), 0.f);
    key[j] = ((u64)__builtin_bit_cast(unsigned, d) << 32) | (unsigned)m;
  }
  u64 gk[4];
  #pragma unroll
  for (int g4 = 0; g4 < 4; ++g4) gk[g4] = min8(key + g4 * 8);
  int keep = 0;
  #pragma unroll 1
  for (int r = 0; r < 24; ++r) {
    u64 kk = kmin(kmin(gk[0], gk[1]), kmin(gk[2], gk[3]));
    #pragma unroll
    for (int off = 32; off >= 1; off >>= 1) {
      const u64 ok = __shfl_xor(kk, off);
      kk = kmin(ok, kk);
    }
    const unsigned wm = (unsigned)kk;            // winner m (uniform)
    if (lane == r) keep = (int)wm;
    if (lane == (int)(wm & 63)) {                // only winning lane edits its groups
      const int j = (int)(wm >> 6);              // 0..31
      if (j < 16) {
        if (j < 8) { inv8(key,      j);      gk[0] = min8(key);      }
        else       { inv8(key + 8,  j - 8);  gk[1] = min8(key + 8);  }
      } else {
        if (j < 24){ inv8(key + 16, j - 16); gk[2] = min8(key + 16); }
        else       { inv8(key + 24, j - 24); gk[3] = min8(key + 24); }
      }
    }
  }
  if (lane < 24) idxout[(size_t)(b * 2048 + q) * 24 + lane] = keep;
}

// ---- K3: per-wave (2 points, 48 rows): groupnorm+concat -> 2 pre res_blocks -> max over K ----
__global__ __launch_bounds__(256, 2) void k_pre(
    const float* __restrict__ features, const int* __restrict__ idxin,
    const _Float16* __restrict__ wp, const float* __restrict__ alpha, const float* __restrict__ beta,
    const float* __restrict__ b1, const float* __restrict__ g1, const float* __restrict__ bb1,
    const float* __restrict__ b2, const float* __restrict__ g2, const float* __restrict__ bb2,
    _Float16* __restrict__ h0) {
  __shared__ _Float16 lds[4][48 * 128];
  const int wid = threadIdx.x >> 6, lane = threadIdx.x & 63;
  _Float16* L = lds[wid];
  const int wgl = blockIdx.x * 4 + wid;
  const int p0 = wgl * 2;
  const int b = p0 >> 11;
  const float* fb = features + (size_t)b * 2048 * 64;
  {
    const int c = lane;
    const float al = alpha[c], be = beta[c];
    #pragma unroll 1
    for (int pp = 0; pp < 2; ++pp) {
      const int p = p0 + pp;
      const int n = p & 2047;
      const int* ip = idxin + (size_t)p * 24;
      const float center = fb[n * 64 + c];
      float v[24]; float su = 0.f, sq = 0.f;
      #pragma unroll
      for (int k = 0; k < 24; ++k) {
        v[k] = fb[ip[k] * 64 + c];
        su += v[k]; sq = fmaf(v[k], v[k], sq);
      }
      const float mean = su * (1.f / 24.f);
      const float var = fmaxf((sq - 24.f * mean * mean) * (1.f / 23.f), 0.f);
      const float rs = 1.f / fmaxf(sqrtf(var), 1e-6f);
      const float c1 = rs * al;
      const float c0 = be - mean * c1 - center;
      const _Float16 ch = (_Float16)center;
      #pragma unroll
      for (int k = 0; k < 24; ++k) {
        const int row = pp * 24 + k;
        stH(L, row, c, ch);
        stH(L, row, 64 + c, (_Float16)fmaf(v[k], c1, c0));
      }
    }
  }
  __threadfence_block();
  const int g = lane >> 4, cr = lane & 15;
  half8 xres[3][4];
  #pragma unroll
  for (int mt = 0; mt < 3; ++mt)
    #pragma unroll
    for (int q = 0; q < 4; ++q)
      xres[mt][q] = ldA(L, mt * 16 + 4 * g + q, cr);
  res_block_dev<3, 0>(L, wp,         wp + 18432,  b1,       g1,       bb1,       b2,       g2,       bb2,       xres, lane, nullptr);
  res_block_dev<3, 1>(L, wp + 36864, wp + 55296,  b1 + 128, g1 + 128, bb1 + 128, b2 + 128, g2 + 128, bb2 + 128, xres, lane, nullptr);
  // max over the 24 rows of each point (rows 0..23 -> p0, 24..47 -> p0+1), all in f16
  half8 m0 = hmax8(hmax8(xres[0][0], xres[0][1]), hmax8(xres[0][2], xres[0][3]));
  m0 = hmax8(m0, shfl_h8(m0, 16));
  m0 = hmax8(m0, shfl_h8(m0, 32));
  half8 m1 = hmax8(hmax8(xres[1][0], xres[1][1]), hmax8(xres[1][2], xres[1][3]));
  m1 = hmax8(m1, shfl_h8(m1, 16));          // g0/g1 hold rows16..23 (p0); g2/g3 rows24..31 (p1)
  const half8 m1o = shfl_h8(m1, 32);        // bring p1-part to g0/g1 side
  half8 m2 = hmax8(hmax8(xres[2][0], xres[2][1]), hmax8(xres[2][2], xres[2][3]));
  m2 = hmax8(m2, shfl_h8(m2, 16));
  m2 = hmax8(m2, shfl_h8(m2, 32));
  if (g == 0) *(half8*)(h0 + (size_t)p0 * 128 + cr * 8)       = hmax8(m0, m1);
  if (g == 1) *(half8*)(h0 + (size_t)(p0 + 1) * 128 + cr * 8) = hmax8(m2, m1o);
}

// ---- K4: pos stage, per-wave 32 rows of h0 -> 2 res_blocks -> h1 (f32) ----
__global__ __launch_bounds__(128, 2) void k_pos(
    const _Float16* __restrict__ h0, const _Float16* __restrict__ wp,
    const float* __restrict__ b1, const float* __restrict__ g1, const float* __restrict__ bb1,
    const float* __restrict__ b2, const float* __restrict__ g2, const float* __restrict__ bb2,
    float* __restrict__ h1) {
  __shared__ _Float16 lds[2][32 * 128];
  const int wid = threadIdx.x >> 6, lane = threadIdx.x & 63;
  _Float16* L = lds[wid];
  const int wgl = blockIdx.x * 2 + wid;
  const size_t rowbase = (size_t)wgl * 32;
  #pragma unroll
  for (int i = 0; i < 8; ++i) {
    const int r = i * 4 + (lane >> 4), ch = lane & 15;
    const half8 tv = *(const half8*)(h0 + (rowbase + r) * 128 + ch * 8);
    stA(L, r, ch, tv);
  }
  __threadfence_block();
  const int g = lane >> 4, cr = lane & 15;
  half8 xres[2][4];
  #pragma unroll
  for (int mt = 0; mt < 2; ++mt)
    #pragma unroll
    for (int q = 0; q < 4; ++q)
      xres[mt][q] = ldA(L, mt * 16 + 4 * g + q, cr);
  res_block_dev<2, 0>(L, wp + 73728,  wp + 92160,  b1,       g1,       bb1,       b2,       g2,       bb2,       xres, lane, nullptr);
  res_block_dev<2, 2>(L, wp + 110592, wp + 129024, b1 + 128, g1 + 128, bb1 + 128, b2 + 128, g2 + 128, bb2 + 128, xres, lane, h1 + rowbase * 128);
}

// ---- K5: gather new_features (h1 by fps_idx, float4) + new_xyz ----
__global__ __launch_bounds__(256) void k_gather(const float* __restrict__ h1, const float* __restrict__ xyz,
                                                const int* __restrict__ fps, float* __restrict__ out) {
  const int i = blockIdx.x * 256 + threadIdx.x;
  const int FEAT4 = 8 * 1024 * 32;   // 262144 float4 elements
  if (i < FEAT4) {
    const int c4 = i & 31, m = (i >> 5) & 1023, b = i >> 15;
    const int n = fps[b * 1024 + m];
    const f32x4 v = *(const f32x4*)(h1 + ((size_t)(b * 2048 + n)) * 128 + c4 * 4);
    *(f32x4*)(out + (size_t)i * 4) = v;
  } else {
    const int jj = i - FEAT4;
    if (jj < 8 * 1024 * 3) {
      const int dd = jj % 3, m = (jj / 3) & 1023, b = jj / 3072;
      const int n = fps[b * 1024 + m];
      out[8 * 1024 * 128 + jj] = xyz[((size_t)(b * 2048 + n)) * 3 + dd];
    }
  }
}

extern "C" void kernel_launch(void* const* d_in, const int* in_sizes, int n_in,
                              void* d_out, int out_size, void* d_ws, size_t ws_size,
                              hipStream_t stream) {
  const float* features = (const float*)d_in[0];
  const float* xyz      = (const float*)d_in[1];
  const int*   fps      = (const int*)d_in[2];
  const float* alpha    = (const float*)d_in[3];
  const float* beta     = (const float*)d_in[4];
  const float* pre_w1   = (const float*)d_in[5];
  const float* pre_b1   = (const float*)d_in[6];
  const float* pre_g1   = (const float*)d_in[7];
  const float* pre_bb1  = (const float*)d_in[8];
  const float* pre_w2   = (const float*)d_in[9];
  const float* pre_b2   = (const float*)d_in[10];
  const float* pre_g2   = (const float*)d_in[11];
  const float* pre_bb2  = (const float*)d_in[12];
  const float* pos_w1   = (const float*)d_in[13];
  const float* pos_b1   = (const float*)d_in[14];
  const float* pos_g1   = (const float*)d_in[15];
  const float* pos_bb1  = (const float*)d_in[16];
  const float* pos_w2   = (const float*)d_in[17];
  const float* pos_b2   = (const float*)d_in[18];
  const float* pos_g2   = (const float*)d_in[19];
  const float* pos_bb2  = (const float*)d_in[20];
  (void)in_sizes; (void)n_in; (void)out_size; (void)ws_size;

  char* ws = (char*)d_ws;                     // needs ~14.3 MB
  _Float16* wp   = (_Float16*)(ws);           // [0, 294912)
  int*      idxb = (int*)(ws + 524288);       // [512K, 2M)
  _Float16* h0   = (_Float16*)(ws + 2097152); // [2M, 6M)
  float*    h1   = (float*)(ws + 6291456);    // [6M, 14M)

  k_pack<<<dim3(576), dim3(256), 0, stream>>>(pre_w1, pre_w2, pos_w1, pos_w2, wp);
  k_knn<<<dim3(4096), dim3(256), 0, stream>>>(xyz, idxb);
  k_pre<<<dim3(2048), dim3(256), 0, stream>>>(features, idxb, wp, alpha, beta,
      pre_b1, pre_g1, pre_bb1, pre_b2, pre_g2, pre_bb2, h0);
  k_pos<<<dim3(256), dim3(128), 0, stream>>>(h0, wp,
      pos_b1, pos_g1, pos_bb1, pos_b2, pos_g2, pos_bb2, h1);
  k_gather<<<dim3(1120), dim3(256), 0, stream>>>(h1, xyz, fps, (float*)d_out);
}

// Round 6
// 164.037 us; speedup vs baseline: 2.7006x; 1.4712x over previous
//
#include <hip/hip_runtime.h>

// PointMLP stage: KNN(24) -> groupnorm+concat -> 2x res_block (D=128) -> max over K
//                 -> 2x res_block -> gather by fps_idx.
// fp16 MFMA (16x16x32); LN stats: mean via 9th MFMA tile (B = rowsum broadcast),
// variance via packed f32 + DPP 16-lane all-reduce (no DS shuffles).
// KNN: u64 keys (dist_bits<<32 | idx); threshold = 24th-smallest lane-min (bitonic),
// compact candidates (~30 expected) to LDS, one final 64-lane bitonic sort.
// ws: wp[0,294912) fp16 weights (9 tiles/matrix); idx[512K,2M); h0[2M,6M) f16; h1[6M,14M) f32.

typedef _Float16 half8 __attribute__((ext_vector_type(8)));
typedef _Float16 h2v   __attribute__((ext_vector_type(2)));
typedef float    f32x4 __attribute__((ext_vector_type(4)));
typedef unsigned long long u64;

#define DEVINL __device__ __forceinline__

union H8 { half8 v; h2v p[4]; int w[4]; };

DEVINL f32x4 splat4(float s) { f32x4 r = {s, s, s, s}; return r; }

DEVINL _Float16 hmax1(_Float16 a, _Float16 b) { return a > b ? a : b; }
DEVINL h2v hmax2v(h2v a, h2v b) {
  h2v r; r[0] = hmax1(a[0], b[0]); r[1] = hmax1(a[1], b[1]); return r;
}
DEVINL h2v cvt2h(float lo, float hi) {
  return __builtin_bit_cast(h2v, __builtin_amdgcn_cvt_pkrtz(lo, hi));
}
DEVINL half8 hmax8(half8 a, half8 b) {
  H8 A, B, R; A.v = a; B.v = b;
  #pragma unroll
  for (int e = 0; e < 4; ++e) R.p[e] = hmax2v(A.p[e], B.p[e]);
  return R.v;
}
DEVINL half8 shfl_h8(half8 x, int m) {
  H8 X; X.v = x;
  #pragma unroll
  for (int e = 0; e < 4; ++e) X.w[e] = __shfl_xor(X.w[e], m);
  return X.v;
}

// 16-lane (DPP row) all-reduce add: quad xor1, quad xor2, half-mirror, mirror.
DEVINL float dpp_add16(float x) {
  int v = __builtin_bit_cast(int, x);
  x += __builtin_bit_cast(float, __builtin_amdgcn_update_dpp(v, v, 0xB1, 0xF, 0xF, true));
  v = __builtin_bit_cast(int, x);
  x += __builtin_bit_cast(float, __builtin_amdgcn_update_dpp(v, v, 0x4E, 0xF, 0xF, true));
  v = __builtin_bit_cast(int, x);
  x += __builtin_bit_cast(float, __builtin_amdgcn_update_dpp(v, v, 0x141, 0xF, 0xF, true));
  v = __builtin_bit_cast(int, x);
  x += __builtin_bit_cast(float, __builtin_amdgcn_update_dpp(v, v, 0x140, 0xF, 0xF, true));
  return x;
}

// ---- swizzled LDS helpers: row stride 256B, XOR 16B-chunk swizzle with (row&7) ----
DEVINL void stH(_Float16* L, int row, int col, _Float16 v) {
  const int b2 = col * 2;
  *(_Float16*)((char*)L + row * 256 + (((b2 >> 4) ^ (row & 7)) << 4) + (b2 & 15)) = v;
}
DEVINL half8 ldA(const _Float16* L, int row, int ch) {
  return *(const half8*)((const char*)L + row * 256 + ((ch ^ (row & 7)) << 4));
}
DEVINL void stA(_Float16* L, int row, int ch, half8 v) {
  *(half8*)((char*)L + row * 256 + ((ch ^ (row & 7)) << 4)) = v;
}

// ---- A(from LDS) @ B(9-tile frag-packed W): tiles 0..7 = outputs, tile 8 = rowsum ----
template<int MT>
DEVINL void mm_dev(const _Float16* L, const _Float16* __restrict__ W, f32x4 acc[MT][9], int lane) {
  const int g = lane >> 4, r = lane & 15;
  #pragma unroll
  for (int s = 0; s < 4; ++s) {
    half8 bfr[9];
    #pragma unroll
    for (int t = 0; t < 9; ++t)
      bfr[t] = *(const half8*)(W + (((s * 9 + t) * 64 + lane) * 8));
    #pragma unroll
    for (int mt = 0; mt < MT; ++mt) {
      const half8 a = ldA(L, mt * 16 + r, s * 4 + g);
      #pragma unroll
      for (int t = 0; t < 9; ++t)
        acc[mt][t] = __builtin_amdgcn_mfma_f32_16x16x32_f16(a, bfr[t], acc[mt][t], 0, 0, 0);
    }
  }
}

// ---- bias + LayerNorm; mean from acc[mt][8] (MFMA rowsum) + sum(bias); var via DPP reduce ----
template<int MT>
DEVINL void epi_ln(f32x4 acc[MT][9], const float* __restrict__ bv, const float* __restrict__ gv,
                   const float* __restrict__ bbv, int lane) {
  const int cr = lane & 15;
  const f32x4 bp0 = *(const f32x4*)(bv + cr * 8),  bp1 = *(const f32x4*)(bv + cr * 8 + 4);
  const f32x4 gp0 = *(const f32x4*)(gv + cr * 8),  gp1 = *(const f32x4*)(gv + cr * 8 + 4);
  const f32x4 ap0 = *(const f32x4*)(bbv + cr * 8), ap1 = *(const f32x4*)(bbv + cr * 8 + 4);
  const f32x4 bs4 = bp0 + bp1;
  const float sb = dpp_add16(bs4[0] + bs4[1] + bs4[2] + bs4[3]);
  #pragma unroll
  for (int mt = 0; mt < MT; ++mt) {
    f32x4 sq4 = splat4(0.f);
    #pragma unroll
    for (int t = 0; t < 8; ++t) {
      const float bias = (t < 4) ? bp0[t & 3] : bp1[t & 3];
      acc[mt][t] = acc[mt][t] + splat4(bias);
      sq4 = sq4 + acc[mt][t] * acc[mt][t];
    }
    #pragma unroll
    for (int q = 0; q < 4; ++q) sq4[q] = dpp_add16(sq4[q]);
    const f32x4 mean = (acc[mt][8] + splat4(sb)) * splat4(1.f / 128.f);
    f32x4 rstd;
    #pragma unroll
    for (int q = 0; q < 4; ++q) {
      const float var = fmaxf(sq4[q] * (1.f / 128.f) - mean[q] * mean[q], 0.f);
      rstd[q] = rsqrtf(var + 1e-5f);
    }
    #pragma unroll
    for (int t = 0; t < 8; ++t) {
      const float gs = (t < 4) ? gp0[t & 3] : gp1[t & 3];
      const float as = (t < 4) ? ap0[t & 3] : ap1[t & 3];
      acc[mt][t] = (acc[mt][t] - mean) * rstd * splat4(gs) + splat4(as);
    }
  }
}

// ---- full res_block. xres[mt][q]: input X row (mt*16+4g+q), channels cr*8.. (f16).
// MODE: 0 = store out rows to LDS + update xres; 1 = update xres only; 2 = f32 rows to gdst.
template<int MT, int MODE>
DEVINL void res_block_dev(_Float16* L, const _Float16* __restrict__ W1, const _Float16* __restrict__ W2,
                          const float* b1, const float* g1, const float* bb1,
                          const float* b2, const float* g2, const float* bb2,
                          half8 xres[MT][4], int lane, float* __restrict__ gdst) {
  const int g = lane >> 4, cr = lane & 15;
  const h2v zero2 = {(_Float16)0, (_Float16)0};
  f32x4 acc[MT][9];
  #pragma unroll
  for (int mt = 0; mt < MT; ++mt)
    #pragma unroll
    for (int t = 0; t < 9; ++t) acc[mt][t] = splat4(0.f);
  mm_dev<MT>(L, W1, acc, lane);
  epi_ln<MT>(acc, b1, g1, bb1, lane);
  __threadfence_block();
  #pragma unroll
  for (int mt = 0; mt < MT; ++mt)
    #pragma unroll
    for (int q = 0; q < 4; ++q) {
      H8 hv;
      #pragma unroll
      for (int e = 0; e < 4; ++e)
        hv.p[e] = hmax2v(cvt2h(acc[mt][2 * e][q], acc[mt][2 * e + 1][q]), zero2);
      stA(L, mt * 16 + 4 * g + q, cr, hv.v);
    }
  #pragma unroll
  for (int mt = 0; mt < MT; ++mt)
    #pragma unroll
    for (int t = 0; t < 9; ++t) acc[mt][t] = splat4(0.f);
  __threadfence_block();
  mm_dev<MT>(L, W2, acc, lane);
  epi_ln<MT>(acc, b2, g2, bb2, lane);
  if constexpr (MODE == 0) __threadfence_block();
  #pragma unroll
  for (int mt = 0; mt < MT; ++mt)
    #pragma unroll
    for (int q = 0; q < 4; ++q) {
      const int row = mt * 16 + 4 * g + q;
      if constexpr (MODE == 2) {
        f32x4 lo, hi;
        #pragma unroll
        for (int e = 0; e < 4; ++e) {
          lo[e] = fmaxf(acc[mt][e][q]     + (float)xres[mt][q][e],     0.f);
          hi[e] = fmaxf(acc[mt][e + 4][q] + (float)xres[mt][q][e + 4], 0.f);
        }
        *(f32x4*)(gdst + row * 128 + cr * 8)     = lo;
        *(f32x4*)(gdst + row * 128 + cr * 8 + 4) = hi;
      } else {
        H8 s;
        #pragma unroll
        for (int e = 0; e < 4; ++e)
          s.p[e] = cvt2h(acc[mt][2 * e][q], acc[mt][2 * e + 1][q]);
        H8 z; z.v = s.v + xres[mt][q];
        #pragma unroll
        for (int e = 0; e < 4; ++e) z.p[e] = hmax2v(z.p[e], zero2);
        xres[mt][q] = z.v;
        if constexpr (MODE == 0) stA(L, row, cr, z.v);
      }
    }
  if constexpr (MODE == 0) __threadfence_block();
}

// ---- K0: pack 8 weight matrices into 9-tile fp16 B-fragment order (tile 8 = rowsum bcast) ----
__global__ __launch_bounds__(256) void k_pack(const float* __restrict__ preW1, const float* __restrict__ preW2,
                                              const float* __restrict__ posW1, const float* __restrict__ posW2,
                                              _Float16* __restrict__ wp) {
  const int o = blockIdx.x * 256 + threadIdx.x;   // 147456 total (576 blocks)
  const int mat = o / 18432, rem = o % 18432;
  const int frag = rem >> 9, li = (rem >> 3) & 63, j = rem & 7;
  const int s = frag / 9, t = frag % 9;
  const int k = s * 32 + ((li >> 4) << 3) + j;
  const int blk = (mat >> 1) & 1, which = mat & 1;
  const float* base = (mat < 4) ? (which ? preW2 : preW1) : (which ? posW2 : posW1);
  const float* Wm = base + blk * 16384;
  float val;
  if (t < 8) {
    val = Wm[k * 128 + (li & 15) * 8 + t];
  } else {
    float ssum = 0.f;
    for (int n = 0; n < 128; ++n) ssum += Wm[k * 128 + n];
    val = ssum;
  }
  wp[o] = (_Float16)val;
}

// ---- KNN helpers: u64 key = (f32bits(d) << 32) | m  (d >= 0) ----
DEVINL u64 kmin(u64 a, u64 b) { return a < b ? a : b; }
DEVINL u64 kmax(u64 a, u64 b) { return a > b ? a : b; }
DEVINL u64 min8(const u64* k) {
  u64 a = kmin(k[0], k[1]), b = kmin(k[2], k[3]);
  u64 c = kmin(k[4], k[5]), d = kmin(k[6], k[7]);
  return kmin(kmin(a, b), kmin(c, d));
}
DEVINL void inv8(u64* k, int j) {
  #pragma unroll
  for (int s = 0; s < 8; ++s) k[s] = (s == j) ? ~0ULL : k[s];
}
// 64-lane bitonic sort (ascending by lane index), one u64 per lane.
DEVINL u64 bitonic64(u64 v, int lane) {
  #pragma unroll
  for (int k = 2; k <= 64; k <<= 1) {
    #pragma unroll
    for (int j = k >> 1; j > 0; j >>= 1) {
      const u64 o = __shfl_xor(v, j);
      const bool up = ((lane & k) == 0);
      const bool lower = ((lane & j) == 0);
      v = (lower == up) ? kmin(v, o) : kmax(v, o);
    }
  }
  return v;
}

// ---- K1: exact 24-NN per point, tie-break = smaller index (u64 lex order) ----
__global__ __launch_bounds__(256) void k_knn(const float* __restrict__ xyz, int* __restrict__ idxout) {
  __shared__ float sx[2048], sy[2048], sz[2048];
  __shared__ u64 scand[4][64];
  const int b = blockIdx.x >> 9;
  const int qbase = (blockIdx.x & 511) * 4;
  const float* xb = xyz + (size_t)b * 2048 * 3;
  for (int i = threadIdx.x; i < 2048; i += 256) {
    sx[i] = xb[i * 3 + 0]; sy[i] = xb[i * 3 + 1]; sz[i] = xb[i * 3 + 2];
  }
  __syncthreads();
  const int wid = threadIdx.x >> 6, lane = threadIdx.x & 63;
  const int q = qbase + wid;
  const float qx = sx[q], qy = sy[q], qz = sz[q];
  const float q2 = qx * qx + qy * qy + qz * qz;
  u64 key[32];
  u64 lmin = ~0ULL;
  #pragma unroll
  for (int j = 0; j < 32; ++j) {
    const int m = j * 64 + lane;
    const float mx = sx[m], my = sy[m], mz = sz[m];
    const float m2 = mx * mx + my * my + mz * mz;
    const float d = fmaxf(q2 + m2 - 2.f * (qx * mx + qy * my + qz * mz), 0.f);
    key[j] = ((u64)__builtin_bit_cast(unsigned, d) << 32) | (unsigned)m;
    lmin = kmin(lmin, key[j]);
  }
  // threshold = 24th-smallest lane-min  =>  #(keys <= t) >= 24
  const u64 t = __shfl(bitonic64(lmin, lane), 23);
  // count and prefix-scan candidates
  int c = 0;
  #pragma unroll
  for (int j = 0; j < 32; ++j) c += (key[j] <= t) ? 1 : 0;
  int inc = c;
  #pragma unroll
  for (int off = 1; off < 64; off <<= 1) {
    const int n = __shfl_up(inc, off);
    if (lane >= off) inc += n;
  }
  const int T = __shfl(inc, 63);
  if (T <= 64) {
    int idx = inc - c;                      // exclusive prefix
    #pragma unroll
    for (int j = 0; j < 32; ++j)
      if (key[j] <= t) { scand[wid][idx] = key[j]; ++idx; }
    __threadfence_block();
    u64 cand = (lane < T) ? scand[wid][lane] : ~0ULL;
    cand = bitonic64(cand, lane);
    if (lane < 24) idxout[(size_t)(b * 2048 + q) * 24 + lane] = (int)(unsigned)cand;
  } else {
    // exact fallback (never expected on this data): 24-round tournament
    u64 gk[4];
    #pragma unroll
    for (int g4 = 0; g4 < 4; ++g4) gk[g4] = min8(key + g4 * 8);
    int keep = 0;
    #pragma unroll 1
    for (int r = 0; r < 24; ++r) {
      u64 kk = kmin(kmin(gk[0], gk[1]), kmin(gk[2], gk[3]));
      #pragma unroll
      for (int off = 32; off >= 1; off >>= 1) kk = kmin(__shfl_xor(kk, off), kk);
      const unsigned wm = (unsigned)kk;
      if (lane == r) keep = (int)wm;
      if (lane == (int)(wm & 63)) {
        const int j = (int)(wm >> 6);
        if (j < 16) {
          if (j < 8) { inv8(key,      j);      gk[0] = min8(key);      }
          else       { inv8(key + 8,  j - 8);  gk[1] = min8(key + 8);  }
        } else {
          if (j < 24){ inv8(key + 16, j - 16); gk[2] = min8(key + 16); }
          else       { inv8(key + 24, j - 24); gk[3] = min8(key + 24); }
        }
      }
    }
    if (lane < 24) idxout[(size_t)(b * 2048 + q) * 24 + lane] = keep;
  }
}

// ---- K3: per-wave (2 points, 48 rows): groupnorm+concat -> 2 pre res_blocks -> max over K ----
__global__ __launch_bounds__(256, 2) void k_pre(
    const float* __restrict__ features, const int* __restrict__ idxin,
    const _Float16* __restrict__ wp, const float* __restrict__ alpha, const float* __restrict__ beta,
    const float* __restrict__ b1, const float* __restrict__ g1, const float* __restrict__ bb1,
    const float* __restrict__ b2, const float* __restrict__ g2, const float* __restrict__ bb2,
    _Float16* __restrict__ h0) {
  __shared__ _Float16 lds[4][48 * 128];
  const int wid = threadIdx.x >> 6, lane = threadIdx.x & 63;
  _Float16* L = lds[wid];
  const int wgl = blockIdx.x * 4 + wid;
  const int p0 = wgl * 2;
  const int b = p0 >> 11;
  const float* fb = features + (size_t)b * 2048 * 64;
  {
    const int c = lane;
    const float al = alpha[c], be = beta[c];
    #pragma unroll 1
    for (int pp = 0; pp < 2; ++pp) {
      const int p = p0 + pp;
      const int n = p & 2047;
      const int* ip = idxin + (size_t)p * 24;
      const float center = fb[n * 64 + c];
      float v[24]; float su = 0.f, sq = 0.f;
      #pragma unroll
      for (int k = 0; k < 24; ++k) {
        v[k] = fb[ip[k] * 64 + c];
        su += v[k]; sq = fmaf(v[k], v[k], sq);
      }
      const float mean = su * (1.f / 24.f);
      const float var = fmaxf((sq - 24.f * mean * mean) * (1.f / 23.f), 0.f);
      const float rs = 1.f / fmaxf(sqrtf(var), 1e-6f);
      const float c1 = rs * al;
      const float c0 = be - mean * c1 - center;
      const _Float16 ch = (_Float16)center;
      #pragma unroll
      for (int k = 0; k < 24; ++k) {
        const int row = pp * 24 + k;
        stH(L, row, c, ch);
        stH(L, row, 64 + c, (_Float16)fmaf(v[k], c1, c0));
      }
    }
  }
  __threadfence_block();
  const int g = lane >> 4, cr = lane & 15;
  half8 xres[3][4];
  #pragma unroll
  for (int mt = 0; mt < 3; ++mt)
    #pragma unroll
    for (int q = 0; q < 4; ++q)
      xres[mt][q] = ldA(L, mt * 16 + 4 * g + q, cr);
  res_block_dev<3, 0>(L, wp,         wp + 18432,  b1,       g1,       bb1,       b2,       g2,       bb2,       xres, lane, nullptr);
  res_block_dev<3, 1>(L, wp + 36864, wp + 55296,  b1 + 128, g1 + 128, bb1 + 128, b2 + 128, g2 + 128, bb2 + 128, xres, lane, nullptr);
  // max over the 24 rows of each point (rows 0..23 -> p0, 24..47 -> p0+1), all in f16
  half8 m0 = hmax8(hmax8(xres[0][0], xres[0][1]), hmax8(xres[0][2], xres[0][3]));
  m0 = hmax8(m0, shfl_h8(m0, 16));
  m0 = hmax8(m0, shfl_h8(m0, 32));
  half8 m1 = hmax8(hmax8(xres[1][0], xres[1][1]), hmax8(xres[1][2], xres[1][3]));
  m1 = hmax8(m1, shfl_h8(m1, 16));          // g0/g1 hold rows16..23 (p0); g2/g3 rows24..31 (p1)
  const half8 m1o = shfl_h8(m1, 32);        // bring p1-part to g0/g1 side
  half8 m2 = hmax8(hmax8(xres[2][0], xres[2][1]), hmax8(xres[2][2], xres[2][3]));
  m2 = hmax8(m2, shfl_h8(m2, 16));
  m2 = hmax8(m2, shfl_h8(m2, 32));
  if (g == 0) *(half8*)(h0 + (size_t)p0 * 128 + cr * 8)       = hmax8(m0, m1);
  if (g == 1) *(half8*)(h0 + (size_t)(p0 + 1) * 128 + cr * 8) = hmax8(m2, m1o);
}

// ---- K4: pos stage, per-wave 32 rows of h0 -> 2 res_blocks -> h1 (f32) ----
__global__ __launch_bounds__(128, 2) void k_pos(
    const _Float16* __restrict__ h0, const _Float16* __restrict__ wp,
    const float* __restrict__ b1, const float* __restrict__ g1, const float* __restrict__ bb1,
    const float* __restrict__ b2, const float* __restrict__ g2, const float* __restrict__ bb2,
    float* __restrict__ h1) {
  __shared__ _Float16 lds[2][32 * 128];
  const int wid = threadIdx.x >> 6, lane = threadIdx.x & 63;
  _Float16* L = lds[wid];
  const int wgl = blockIdx.x * 2 + wid;
  const size_t rowbase = (size_t)wgl * 32;
  #pragma unroll
  for (int i = 0; i < 8; ++i) {
    const int r = i * 4 + (lane >> 4), ch = lane & 15;
    const half8 tv = *(const half8*)(h0 + (rowbase + r) * 128 + ch * 8);
    stA(L, r, ch, tv);
  }
  __threadfence_block();
  const int g = lane >> 4, cr = lane & 15;
  half8 xres[2][4];
  #pragma unroll
  for (int mt = 0; mt < 2; ++mt)
    #pragma unroll
    for (int q = 0; q < 4; ++q)
      xres[mt][q] = ldA(L, mt * 16 + 4 * g + q, cr);
  res_block_dev<2, 0>(L, wp + 73728,  wp + 92160,  b1,       g1,       bb1,       b2,       g2,       bb2,       xres, lane, nullptr);
  res_block_dev<2, 2>(L, wp + 110592, wp + 129024, b1 + 128, g1 + 128, bb1 + 128, b2 + 128, g2 + 128, bb2 + 128, xres, lane, h1 + rowbase * 128);
}

// ---- K5: gather new_features (h1 by fps_idx, float4) + new_xyz ----
__global__ __launch_bounds__(256) void k_gather(const float* __restrict__ h1, const float* __restrict__ xyz,
                                                const int* __restrict__ fps, float* __restrict__ out) {
  const int i = blockIdx.x * 256 + threadIdx.x;
  const int FEAT4 = 8 * 1024 * 32;   // 262144 float4 elements
  if (i < FEAT4) {
    const int c4 = i & 31, m = (i >> 5) & 1023, b = i >> 15;
    const int n = fps[b * 1024 + m];
    const f32x4 v = *(const f32x4*)(h1 + ((size_t)(b * 2048 + n)) * 128 + c4 * 4);
    *(f32x4*)(out + (size_t)i * 4) = v;
  } else {
    const int jj = i - FEAT4;
    if (jj < 8 * 1024 * 3) {
      const int dd = jj % 3, m = (jj / 3) & 1023, b = jj / 3072;
      const int n = fps[b * 1024 + m];
      out[8 * 1024 * 128 + jj] = xyz[((size_t)(b * 2048 + n)) * 3 + dd];
    }
  }
}

extern "C" void kernel_launch(void* const* d_in, const int* in_sizes, int n_in,
                              void* d_out, int out_size, void* d_ws, size_t ws_size,
                              hipStream_t stream) {
  const float* features = (const float*)d_in[0];
  const float* xyz      = (const float*)d_in[1];
  const int*   fps      = (const int*)d_in[2];
  const float* alpha    = (const float*)d_in[3];
  const float* beta     = (const float*)d_in[4];
  const float* pre_w1   = (const float*)d_in[5];
  const float* pre_b1   = (const float*)d_in[6];
  const float* pre_g1   = (const float*)d_in[7];
  const float* pre_bb1  = (const float*)d_in[8];
  const float* pre_w2   = (const float*)d_in[9];
  const float* pre_b2   = (const float*)d_in[10];
  const float* pre_g2   = (const float*)d_in[11];
  const float* pre_bb2  = (const float*)d_in[12];
  const float* pos_w1   = (const float*)d_in[13];
  const float* pos_b1   = (const float*)d_in[14];
  const float* pos_g1   = (const float*)d_in[15];
  const float* pos_bb1  = (const float*)d_in[16];
  const float* pos_w2   = (const float*)d_in[17];
  const float* pos_b2   = (const float*)d_in[18];
  const float* pos_g2   = (const float*)d_in[19];
  const float* pos_bb2  = (const float*)d_in[20];
  (void)in_sizes; (void)n_in; (void)out_size; (void)ws_size;

  char* ws = (char*)d_ws;                     // needs ~14.3 MB
  _Float16* wp   = (_Float16*)(ws);           // [0, 294912)
  int*      idxb = (int*)(ws + 524288);       // [512K, 2M)
  _Float16* h0   = (_Float16*)(ws + 2097152); // [2M, 6M)
  float*    h1   = (float*)(ws + 6291456);    // [6M, 14M)

  k_pack<<<dim3(576), dim3(256), 0, stream>>>(pre_w1, pre_w2, pos_w1, pos_w2, wp);
  k_knn<<<dim3(4096), dim3(256), 0, stream>>>(xyz, idxb);
  k_pre<<<dim3(2048), dim3(256), 0, stream>>>(features, idxb, wp, alpha, beta,
      pre_b1, pre_g1, pre_bb1, pre_b2, pre_g2, pre_bb2, h0);
  k_pos<<<dim3(256), dim3(128), 0, stream>>>(h0, wp,
      pos_b1, pos_g1, pos_bb1, pos_b2, pos_g2, pos_bb2, h1);
  k_gather<<<dim3(1120), dim3(256), 0, stream>>>(h1, xyz, fps, (float*)d_out);
}